// Round 15
// baseline (483.798 us; speedup 1.0000x reference)
//
#include <hip/hip_runtime.h>

typedef unsigned short u16;
typedef unsigned int u32;
typedef unsigned long long u64;

typedef __attribute__((ext_vector_type(8))) short short8;   // 8 bf16 = 4 VGPRs
typedef __attribute__((ext_vector_type(4))) float floatx4;  // MFMA accumulator

__device__ __forceinline__ float b2f(u16 h) {
  u32 u = ((u32)h) << 16;
  return __builtin_bit_cast(float, u);
}
__device__ __forceinline__ u16 f2b(float f) {
  u32 u = __builtin_bit_cast(u32, f);
  u32 r = 0x7FFFu + ((u >> 16) & 1u);  // RNE
  return (u16)((u + r) >> 16);
}

// async global->LDS, 16B per lane. LDS dest = wave-uniform base + lane*16.
__device__ __forceinline__ void gl_lds16(const void* g, void* l) {
  __builtin_amdgcn_global_load_lds(
      (__attribute__((address_space(1))) void*)(u64)g,
      (__attribute__((address_space(3))) void*)(u32)(u64)l, 16, 0, 0);
}

// raw workgroup barrier WITHOUT the compiler's vmcnt(0) drain.
__device__ __forceinline__ void wg_barrier() {
  asm volatile("" ::: "memory");
  __builtin_amdgcn_s_barrier();
  asm volatile("" ::: "memory");
}

// trunc-pack 8 fp32 -> 8 bf16 (verified byte order, round-0 kernel)
__device__ __forceinline__ short8 cvt2(const float4& a, const float4& b) {
  union { u32 w[4]; short8 s; } cv;
  const u32* x = (const u32*)&a;
  const u32* y = (const u32*)&b;
  cv.w[0] = __builtin_amdgcn_perm(x[1], x[0], 0x07060302u);
  cv.w[1] = __builtin_amdgcn_perm(x[3], x[2], 0x07060302u);
  cv.w[2] = __builtin_amdgcn_perm(y[1], y[0], 0x07060302u);
  cv.w[3] = __builtin_amdgcn_perm(y[3], y[2], 0x07060302u);
  return cv.s;
}

enum { EPI_PHI_BIAS = 0, EPI_BIAS = 1, EPI_NONE = 2, EPI_ZSCALE = 3,
       EPI_BIAS_F32 = 4, EPI_ZBIAS_F32 = 5 };

// C[m,n] = sum_k A[m,k] * B[n,k]  (K-contiguous). Round-15: back to the
// R2-verified 128x128x32 geometry (4 waves 2x2, 64x64/wave, acc 64 VGPR)
// for 3 blocks/CU (launch_bounds(256,3): ~150-168 unified regs/wave), with
// R13/14's verified deep-buffer single-barrier discipline. Cross-block TLP
// (12 waves/CU) now covers barrier/wait stalls (m97/m114 mechanism) that a
// 1-block/CU 256^2 config must eat.
//
// Tile LDS layout (R2, refcheck'd): 8KB tile = 128 rows x 4 slots of 16B,
// phys p = R*8 + (u^(R&7)), R=r>>1, u=((r&1)<<2)|c  (conflict-free
// ds_read_b128 and lane-linear staging: slot p = n*256+tid).
//
// bf16 path: A tribuf 3x8K @0, B tribuf 3x8K @24K (48K). Tiles staged 2
// ahead AFTER the barrier. Top-of-iter wait vmcnt(it+1<NIT ? 4 : 0):
//   pre-wait outstanding = {(it)4 kept, (it+1)4 staged during it-1} ->
//   drains (it), keeps (it+1). 2-iter cover for every load. WAR: stage(it+2)
//   overwrites buffers last read at it-1; the top-of-it barrier (reached by
//   every wave after compute(it-1), reads register-consumed) separates.
//
// A_F32 path: A fp32 reg-staged 1 bank (16 VGPR: 2 slots x 2 float4),
// A-LDS dbuf 2x8K @0, B tribuf 3x8K @16K (40K). Issue order per iter:
// B(it+2)x2 @top, A(it+2)x4 @mid. Mid wait vmcnt(pre2?2:0): pre-wait
// {B(it+1)2, A(it+1)4, B(it+2)2} -> drains B(it+1)+A(it+1) (regs for the
// awrite), keeps B(it+2). End: lgkm(0) + barrier publishes tile it+1.
// FIFO walk verified for prologue/steady/tails. Per-wave counters +
// barrier => cross-wave validity (round-3 lesson).
//
// Block swizzle: XCD-chunked remap, N-tiles of one M-slab adjacent;
// gridDim.y==8, (gx*gy)%8==0 all launches. Split-K: bz = kslice*(abmask+1)
// + batch. DUAL: bz picks set 1 (no phi) vs 0 (phi). KSUM (DUAL&&TRANS&&
// phi_on): fused column sums -> atomicAdd ksum_out[batch*1024+col].
template<int EPI, bool A_F32, bool TRANS_OUT, bool DUAL>
__global__ __launch_bounds__(256, 3)
void gemm_bt(const void* __restrict__ Aall, const u16* __restrict__ Ball,
             const float* __restrict__ bias, const float* __restrict__ Zall,
             void* __restrict__ Call,
             int M, int N, int K, int ldA, int ldB, int ldC,
             long sAb, long sBb, long sCb, long sZb, int abmask, int kshift,
             const void* __restrict__ Aall2, const u16* __restrict__ Ball2,
             const float* __restrict__ bias2, void* __restrict__ Call2,
             float* __restrict__ ksum_out)
{
  extern __shared__ char smem[];

  const int tid  = threadIdx.x;
  const int lane = tid & 63;
  const int wave = tid >> 6;
  const int wm = wave >> 1, wn = wave & 1;   // 2x2 waves, 64x64 each
  const int fl = lane & 15;
  const int q  = lane >> 4;
  const int r4 = q * 4;

  // XCD-chunked block swizzle; consecutive remapped ids iterate the 8
  // N-tiles of one M-tile.
  const int orig = blockIdx.x + gridDim.x * blockIdx.y;
  const int nwg8 = (gridDim.x * gridDim.y) >> 3;
  const int wsw  = (orig & 7) * nwg8 + (orig >> 3);
  const int bm0 = (wsw >> 3) * 128;          // gridDim.y == 8 in all launches
  const int bn0 = (wsw & 7) * 128;

  const int bz = blockIdx.z;
  const int abz = bz & abmask;
  const int kbase = (bz >> kshift) * K;

  const void* Asel = Aall; const u16* Bsel = Ball;
  const float* biasSel = bias; void* Csel = Call;
  bool phi_on = true;
  if constexpr (DUAL) {
    if (bz) { Asel = Aall2; Bsel = Ball2; biasSel = bias2; Csel = Call2; phi_on = false; }
  }

  const u16* Bp = Bsel + (size_t)abz * sBb + kbase;

  // ---- staging addresses: slot p = n*256+tid; inverse of phys mapping ----
  const u16* gB[2]; int sLo[2]; int rowc[2][2];  // rowc[n] = {r, c}
  #pragma unroll
  for (int n = 0; n < 2; ++n) {
    int p = n * 256 + tid;
    int R = p >> 3, u = (p & 7) ^ (R & 7);
    int r = (R << 1) | (u >> 2), c = u & 3;
    gB[n] = Bp + (size_t)(bn0 + r) * ldB + c * 8;
    sLo[n] = p * 16;
    rowc[n][0] = r; rowc[n][1] = c;
  }

  // ---- fragment LDS byte offsets (R2 mapping) ----
  int aoff[4], boff[4];
  #pragma unroll
  for (int i = 0; i < 4; ++i) {
    int rb = wn * 64 + i * 16 + fl;
    int Rb = rb >> 1, ub = ((((rb & 1) << 2) | q) ^ (Rb & 7));
    boff[i] = (Rb * 8 + ub) * 16;
    int ra = wm * 64 + i * 16 + fl;
    int Ra = ra >> 1, ua = ((((ra & 1) << 2) | q) ^ (Ra & 7));
    aoff[i] = (Ra * 8 + ua) * 16;
  }

  floatx4 zero = {0.f, 0.f, 0.f, 0.f};
  floatx4 acc[4][4];
  #pragma unroll
  for (int i = 0; i < 4; ++i)
    #pragma unroll
    for (int j = 0; j < 4; ++j) acc[i][j] = zero;

  const int NIT = K >> 5;                 // K-tiles of 32 (NIT >= 8 here)

  if constexpr (A_F32) {
    auto ABUF = [&](int i) -> char* { return smem + (i & 1) * 8192; };
    auto BBUF = [&](int i) -> char* { return smem + 16384 + (i % 3) * 8192; };
    auto stageB3 = [&](int k0, char* bbase) {
      #pragma unroll
      for (int n = 0; n < 2; ++n) gl_lds16(gB[n] + k0, bbase + sLo[n]);
    };

    const float* Af = (const float*)Asel + (size_t)abz * sAb + kbase;
    const float* gAs[2]; int wOff[2];
    #pragma unroll
    for (int n = 0; n < 2; ++n) {
      gAs[n] = Af + (size_t)(bm0 + rowc[n][0]) * ldA + rowc[n][1] * 8;
      wOff[n] = sLo[n];
    }

    float4 Ar[4];                          // one A-tile bank (16 VGPR)
    auto aload = [&](int k0) {
      #pragma unroll
      for (int n = 0; n < 2; ++n) {
        Ar[2 * n]     = *(const float4*)(gAs[n] + k0);
        Ar[2 * n + 1] = *(const float4*)(gAs[n] + k0 + 4);
      }
    };
    auto awrite = [&](char* base) {
      #pragma unroll
      for (int n = 0; n < 2; ++n)
        *(short8*)(base + wOff[n]) = cvt2(Ar[2 * n], Ar[2 * n + 1]);
    };

    short8 aF[4], bF[4];
    auto rdB = [&](const char* bbase) {
      #pragma unroll
      for (int i = 0; i < 4; ++i) bF[i] = *(const short8*)(bbase + boff[i]);
    };
    auto mma2 = [&](const char* abase, int h) {  // mi = 2h, 2h+1
      #pragma unroll
      for (int i = 0; i < 2; ++i) aF[i] = *(const short8*)(abase + aoff[2 * h + i]);
      __builtin_amdgcn_s_setprio(1);
      #pragma unroll
      for (int i = 0; i < 2; ++i)
        #pragma unroll
        for (int ni = 0; ni < 4; ++ni)
          acc[2 * h + i][ni] =
              __builtin_amdgcn_mfma_f32_16x16x32_bf16(aF[i], bF[ni], acc[2 * h + i][ni], 0, 0, 0);
      __builtin_amdgcn_s_setprio(0);
    };

    // prologue (NIT >= 2)
    aload(0);                                           // A(0): 4
    stageB3(0, BBUF(0));                                // B(0): +2
    stageB3(32, BBUF(1));                               // B(1): +2
    asm volatile("s_waitcnt vmcnt(4)" ::: "memory");    // A(0) landed
    awrite(ABUF(0));
    aload(32);                                          // A(1): +4
    asm volatile("s_waitcnt vmcnt(6)" ::: "memory");    // B(0) landed
    asm volatile("s_waitcnt lgkmcnt(0)" ::: "memory");  // A(0) committed
    wg_barrier();                                       // tile 0 published

    for (int it = 0; it < NIT; ++it) {
      const char* Ab = ABUF(it);
      const char* Bb = BBUF(it);
      const bool pre1 = (it + 1 < NIT), pre2 = (it + 2 < NIT);
      if (pre2) stageB3((it + 2) * 32, BBUF(it + 2));
      rdB(Bb);
      mma2(Ab, 0);
      if (pre1) {
        if (pre2) { asm volatile("s_waitcnt vmcnt(2)" ::: "memory"); }  // A(it+1) regs + B(it+1) landed
        else      { asm volatile("s_waitcnt vmcnt(0)" ::: "memory"); }
        awrite(ABUF(it + 1));
        if (pre2) aload((it + 2) * 32);
      }
      mma2(Ab, 1);
      if (pre1) { asm volatile("s_waitcnt lgkmcnt(0)" ::: "memory"); }
      wg_barrier();                        // publish tile it+1; WAR
    }
  } else {
    auto ABUF = [&](int i) -> char* { return smem + (i % 3) * 8192; };
    auto BBUF = [&](int i) -> char* { return smem + 24576 + (i % 3) * 8192; };
    const u16* Ah = (const u16*)Asel + (size_t)abz * sAb + kbase;
    const u16* gA[2];
    #pragma unroll
    for (int n = 0; n < 2; ++n)
      gA[n] = Ah + (size_t)(bm0 + rowc[n][0]) * ldA + rowc[n][1] * 8;
    auto stageT = [&](int k0, char* abase, char* bbase) {  // A then B (4 loads)
      #pragma unroll
      for (int n = 0; n < 2; ++n) gl_lds16(gA[n] + k0, abase + sLo[n]);
      #pragma unroll
      for (int n = 0; n < 2; ++n) gl_lds16(gB[n] + k0, bbase + sLo[n]);
    };
    auto compute = [&](const char* Ab, const char* Bb) {
      short8 aF[4], bF[4];
      #pragma unroll
      for (int i = 0; i < 4; ++i) aF[i] = *(const short8*)(Ab + aoff[i]);
      #pragma unroll
      for (int i = 0; i < 4; ++i) bF[i] = *(const short8*)(Bb + boff[i]);
      __builtin_amdgcn_s_setprio(1);
      #pragma unroll
      for (int mi = 0; mi < 4; ++mi)
        #pragma unroll
        for (int ni = 0; ni < 4; ++ni)
          acc[mi][ni] = __builtin_amdgcn_mfma_f32_16x16x32_bf16(aF[mi], bF[ni], acc[mi][ni], 0, 0, 0);
      __builtin_amdgcn_s_setprio(0);
    };
    // prologue: tiles 0 and 1 in flight (8 loads)
    stageT(0, ABUF(0), BBUF(0));
    stageT(32, ABUF(1), BBUF(1));
    for (int it = 0; it < NIT; ++it) {
      if (it + 1 < NIT) { asm volatile("s_waitcnt vmcnt(4)" ::: "memory"); }  // (it) landed, keep (it+1)
      else              { asm volatile("s_waitcnt vmcnt(0)" ::: "memory"); }
      wg_barrier();                        // publish (it); WAR gate
      if (it + 2 < NIT) stageT((it + 2) * 32, ABUF(it + 2), BBUF(it + 2));
      compute(ABUF(it), BBUF(it));
    }
  }

  if constexpr (!TRANS_OUT) {
    #pragma unroll
    for (int mi = 0; mi < 4; ++mi) {
      #pragma unroll
      for (int ni = 0; ni < 4; ++ni) {
        int col = bn0 + wn * 64 + ni * 16 + fl;
        #pragma unroll
        for (int r = 0; r < 4; ++r) {
          int row = bm0 + wm * 64 + mi * 16 + r4 + r;
          float vv = acc[mi][ni][r];
          if constexpr (EPI == EPI_PHI_BIAS) {
            vv += biasSel[col];
            if (phi_on) vv = __expf(-0.5f * vv * vv);
          }
          if constexpr (EPI == EPI_BIAS || EPI == EPI_BIAS_F32) vv += biasSel[col];
          if constexpr (EPI == EPI_ZSCALE) vv *= Zall[(size_t)abz * sZb + row];
          if constexpr (EPI == EPI_ZBIAS_F32)
            vv = vv * Zall[(size_t)abz * sZb + row] + biasSel[col];
          if constexpr (EPI == EPI_BIAS_F32 || EPI == EPI_ZBIAS_F32)
            ((float*)Csel)[(size_t)bz * sCb + (size_t)row * ldC + col] = vv;
          else
            ((u16*)Csel)[(size_t)bz * sCb + (size_t)row * ldC + col] = f2b(vv);
        }
      }
    }
  } else {
    // transpose tile through LDS, then coalesced 16B stores into [4][N][4096]
    float ks[4] = {0.f, 0.f, 0.f, 0.f};   // fused Ksum column partials
    __syncthreads();                      // all compute reads done, smem free
    u16* sT = (u16*)smem;                 // [128][136] = 34816 B (fits 40960)
    #pragma unroll
    for (int mi = 0; mi < 4; ++mi) {
      #pragma unroll
      for (int ni = 0; ni < 4; ++ni) {
        int colL = wn * 64 + ni * 16 + fl;
        int row0 = wm * 64 + mi * 16 + r4;
        float bcol = biasSel[bn0 + colL];
        ushort4 h;
        #pragma unroll
        for (int r = 0; r < 4; ++r) {
          float vv = acc[mi][ni][r] + bcol;
          if (phi_on) vv = __expf(-0.5f * vv * vv);
          if constexpr (DUAL) ks[ni] += vv;
          ((u16*)&h)[r] = f2b(vv);
        }
        *(ushort4*)(sT + colL * 136 + row0) = h;
      }
    }
    __syncthreads();
    #pragma unroll
    for (int i = 0; i < 8; ++i) {
      int c = tid + i * 256;                // 2048 x 16B chunks
      int dloc = c >> 4, t8 = (c & 15) * 8;
      int4 vv = *(const int4*)(sT + dloc * 136 + t8);
      int gd = bn0 + dloc;
      int gt = bm0 + t8;
      int batch = gt >> 12, tt = gt & 4095;
      *(int4*)((u16*)Csel + ((size_t)batch * N + gd) * 4096 + tt) = vv;
    }
    if constexpr (DUAL) {
      if (phi_on) {                       // K-projection blocks: fused Ksum
        #pragma unroll
        for (int ni = 0; ni < 4; ++ni) {
          float s = ks[ni];
          s += __shfl_xor(s, 16, 64);
          s += __shfl_xor(s, 32, 64);
          if (q == 0)
            atomicAdd(ksum_out + ((bm0 >> 12) << 10) + bn0 + wn * 64 + ni * 16 + fl, s);
        }
      }
    }
  }
}

__global__ __launch_bounds__(256)
void wconv(const float* __restrict__ w0, const float* __restrict__ w1,
           const float* __restrict__ w2, const float* __restrict__ w3,
           u16* __restrict__ dst, float* __restrict__ ksum) {
  if (blockIdx.x == 0) {                 // zero Ksum [4][1024] for fused atomics
    float4 z = {0.f, 0.f, 0.f, 0.f};
    #pragma unroll
    for (int i = 0; i < 4; ++i)
      *(float4*)(ksum + threadIdx.x * 16 + i * 4) = z;
  }
  unsigned e = blockIdx.x * 256 + threadIdx.x;
  int mat = e >> 18;
  size_t off = (size_t)(e & 262143) * 4;
  const float* src = mat == 0 ? w0 : mat == 1 ? w1 : mat == 2 ? w2 : w3;
  float4 v = *(const float4*)(src + off);
  ushort4 h;
  h.x = f2b(v.x); h.y = f2b(v.y); h.z = f2b(v.z); h.w = f2b(v.w);
  *(ushort4*)(dst + (size_t)mat * 1048576 + off) = h;
}

// out[i] = round(sum over 4 K-slices of bf16 partials), 4M elems, slice stride 4M
__global__ __launch_bounds__(256)
void reduce4(const u16* __restrict__ P, u16* __restrict__ out) {
  size_t i = ((size_t)blockIdx.x * 256 + threadIdx.x) * 8;
  int4 a = *(const int4*)(P + i);
  int4 b = *(const int4*)(P + i + 4194304);
  int4 c = *(const int4*)(P + i + 8388608);
  int4 d = *(const int4*)(P + i + 12582912);
  const u16* ha = (const u16*)&a; const u16* hb = (const u16*)&b;
  const u16* hc = (const u16*)&c; const u16* hd = (const u16*)&d;
  ushort4 o0, o1;
  #pragma unroll
  for (int j = 0; j < 8; ++j) {
    float s = b2f(ha[j]) + b2f(hb[j]) + b2f(hc[j]) + b2f(hd[j]);
    ((u16*)(j < 4 ? &o0 : &o1))[j & 3] = f2b(s);
  }
  *(ushort4*)(out + i) = o0;
  *(ushort4*)(out + i + 4) = o1;
}

// Z[t] = 1/(Q[t,:]·Ksum[batch,:] + 1e-6); one wave per token
__global__ __launch_bounds__(256)
void zden(const u16* __restrict__ Qb, const float* __restrict__ Ksum,
          float* __restrict__ Z) {
  int lane = threadIdx.x & 63;
  int t = blockIdx.x * 4 + (threadIdx.x >> 6);
  const u16* qp = Qb + (size_t)t * 1024;
  const float* ks = Ksum + (size_t)(t >> 12) * 1024;
  float s = 0.f;
  #pragma unroll
  for (int i = 0; i < 2; ++i) {
    int idx = i * 512 + lane * 8;
    int4 d = *(const int4*)(qp + idx);
    const u16* h = (const u16*)&d;
    float4 k0 = *(const float4*)(ks + idx);
    float4 k1 = *(const float4*)(ks + idx + 4);
    s += b2f(h[0]) * k0.x + b2f(h[1]) * k0.y + b2f(h[2]) * k0.z + b2f(h[3]) * k0.w
       + b2f(h[4]) * k1.x + b2f(h[5]) * k1.y + b2f(h[6]) * k1.z + b2f(h[7]) * k1.w;
  }
  #pragma unroll
  for (int off = 32; off; off >>= 1) s += __shfl_xor(s, off, 64);
  if (lane == 0) Z[t] = 1.0f / (s + 1e-6f);
}

extern "C" void kernel_launch(void* const* d_in, const int* in_sizes, int n_in,
                              void* d_out, int out_size, void* d_ws, size_t ws_size,
                              hipStream_t stream) {
  const float* q  = (const float*)d_in[0];
  const float* k  = (const float*)d_in[1];
  const float* v  = (const float*)d_in[2];
  const float* Wq = (const float*)d_in[3];
  const float* bq = (const float*)d_in[4];
  const float* Wk = (const float*)d_in[5];
  const float* bk = (const float*)d_in[6];
  const float* Wv = (const float*)d_in[7];
  const float* bv = (const float*)d_in[8];
  const float* Wo = (const float*)d_in[9];
  const float* bo = (const float*)d_in[10];
  float* out = (float*)d_out;

  // workspace layout (~112.1 MiB) with aliasing:
  u16* Wqb = (u16*)d_ws;                 // 4x 1024x1024 bf16 = 8 MiB
  u16* Wkb = Wqb + 1048576;
  u16* Wvb = Wkb + 1048576;
  u16* Wob = Wvb + 1048576;
  u16* Qb  = Wob + 1048576;              // [16384][1024] bf16, 32 MiB
  u16* KT  = Qb  + 16777216;             // [4][1024][4096] bf16, 32 MiB
  u16* VT  = KT  + 16777216;             // [4][1024][4096] bf16, 32 MiB
  u16* KVr = VT  + 16777216;             // [4][1024(d)][1024(l)] bf16, 8 MiB
  float* Ksum = (float*)(KVr + 4194304); // [4][1024] f32 (atomically built)
  float* Z    = Ksum + 4096;             // [16384] f32
  u16* Pkv = Qb;   // S2 split-K partials, before Q-proj overwrites
  u16* Pg  = VT;   // G split-K partials, after VT dead
  u16* Gp  = KT;   // G' [4][1024(n)][1024(d)], after KT dead

  constexpr size_t LDS_F32  = 40960;     // A 2x8K + B 3x8K
  constexpr size_t LDS_BF16 = 49152;     // A 3x8K + B 3x8K

  wconv<<<4096, 256, 0, stream>>>(Wq, Wk, Wv, Wo, Wqb, Ksum);

  // K,V projections in ONE dispatch (grid z: 0=K with phi + fused Ksum,
  // 1=V bias-only). A = fp32 k / v directly (in-kernel conversion).
  dim3 gkv(128, 8, 2);
  gemm_bt<EPI_PHI_BIAS, true, true, true><<<gkv, 256, LDS_F32, stream>>>(
      k, Wkb, bk, nullptr, KT, 16384, 1024, 1024, 1024, 1024, 0,
      0, 0, 0, 0, 0, 30, v, Wvb, bv, VT, Ksum);

  // S2: KVr[d,l] = sum_t KT[d,t]*VT[l,t], split-K x4 (z = kslice*4+batch)
  dim3 g2(8, 8, 16);
  gemm_bt<EPI_NONE, false, false, false><<<g2, 256, LDS_BF16, stream>>>(
      KT, VT, nullptr, nullptr, Pkv, 1024, 1024, 1024, 4096, 4096, 1024,
      4194304L, 4194304L, 1048576L, 0, 3, 2, nullptr, nullptr, nullptr, nullptr, nullptr);
  reduce4<<<2048, 256, 0, stream>>>(Pkv, KVr);

  // Q projection from fp32 q (overwrites partials region — stream-ordered)
  dim3 g1(128, 8, 1);
  gemm_bt<EPI_PHI_BIAS, true, false, false><<<g1, 256, LDS_F32, stream>>>(
      q, Wqb, bq, nullptr, Qb, 16384, 1024, 1024, 1024, 1024, 1024,
      0, 0, 0, 0, 0, 30, nullptr, nullptr, nullptr, nullptr, nullptr);

  zden<<<4096, 256, 0, stream>>>(Qb, Ksum, Z);

  // G'[n,d] = sum_l Wob[n,l]*KVr[d,l], split-K x4 (K=256/slice); Wo folded in.
  dim3 gg(8, 8, 16);
  gemm_bt<EPI_NONE, false, false, false><<<gg, 256, LDS_BF16, stream>>>(
      Wob, KVr, nullptr, nullptr, Pg, 1024, 1024, 256, 1024, 1024, 1024,
      0L, 1048576L, 1048576L, 0, 3, 2, nullptr, nullptr, nullptr, nullptr, nullptr);
  reduce4<<<2048, 256, 0, stream>>>(Pg, Gp);

  // final: out[t,n] = Z[t]*(sum_d Qb[t,d]*G'[n,d]) + bo[n], fp32 out
  dim3 gf(32, 8, 4);
  gemm_bt<EPI_ZBIAS_F32, false, false, false><<<gf, 256, LDS_BF16, stream>>>(
      Qb, Gp, bo, Z, out, 4096, 1024, 1024, 1024, 1024, 1024,
      4194304L, 1048576L, 4194304L, 4096L, 3, 30, nullptr, nullptr, nullptr, nullptr, nullptr);
}

// Round 16
// 419.878 us; speedup vs baseline: 1.1522x; 1.1522x over previous
//
#include <hip/hip_runtime.h>

typedef unsigned short u16;
typedef unsigned int u32;
typedef unsigned long long u64;

typedef __attribute__((ext_vector_type(8))) short short8;   // 8 bf16 = 4 VGPRs
typedef __attribute__((ext_vector_type(4))) float floatx4;  // MFMA accumulator

__device__ __forceinline__ float b2f(u16 h) {
  u32 u = ((u32)h) << 16;
  return __builtin_bit_cast(float, u);
}
__device__ __forceinline__ u16 f2b(float f) {
  u32 u = __builtin_bit_cast(u32, f);
  u32 r = 0x7FFFu + ((u >> 16) & 1u);  // RNE
  return (u16)((u + r) >> 16);
}

// async global->LDS, 16B per lane. LDS dest = wave-uniform base + lane*16.
__device__ __forceinline__ void gl_lds16(const void* g, void* l) {
  __builtin_amdgcn_global_load_lds(
      (__attribute__((address_space(1))) void*)(u64)g,
      (__attribute__((address_space(3))) void*)(u32)(u64)l, 16, 0, 0);
}

// raw workgroup barrier WITHOUT the compiler's vmcnt(0) drain, so
// global_load_lds prefetches stay in flight across it.
__device__ __forceinline__ void wg_barrier() {
  asm volatile("" ::: "memory");
  __builtin_amdgcn_s_barrier();
  asm volatile("" ::: "memory");
}

// trunc-pack 8 fp32 -> 8 bf16 (verified byte order, round-0 kernel)
__device__ __forceinline__ short8 cvt2(const float4& a, const float4& b) {
  union { u32 w[4]; short8 s; } cv;
  const u32* x = (const u32*)&a;
  const u32* y = (const u32*)&b;
  cv.w[0] = __builtin_amdgcn_perm(x[1], x[0], 0x07060302u);
  cv.w[1] = __builtin_amdgcn_perm(x[3], x[2], 0x07060302u);
  cv.w[2] = __builtin_amdgcn_perm(y[1], y[0], 0x07060302u);
  cv.w[3] = __builtin_amdgcn_perm(y[3], y[2], 0x07060302u);
  return cv.s;
}

enum { EPI_PHI_BIAS = 0, EPI_BIAS = 1, EPI_NONE = 2, EPI_ZSCALE = 3,
       EPI_BIAS_F32 = 4, EPI_ZBIAS_F32 = 5 };

// C[m,n] = sum_k A[m,k] * B[n,k]  (K-contiguous). 256x256x64 tile, 8 waves
// (2M x 4N, 128x64 per wave). Per-dispatch rocprof timings swing ±30% across
// runs — judge by totals. SESSION-BEST structure (R13/R14 verified: 415.4 /
// 414.9 us): deep-in-time counted-vmcnt pipelines, one barrier per K-tile.
// R15's 128^2/3-blocks-per-CU variant regressed (483.8): quadrupled barrier
// rate per MFMA + doubled A re-fetch — tile choice is structure-dependent.
//
// A_F32 (round-13, VERIFIED): deep-in-time pipeline, 160K LDS (A dbuf 2x32K,
// B tribuf 3x32K), single 32-VGPR A bank, loads in flight >= 1 iter before
// their wait, ONE barrier/iter, no vmem drain in steady loop.
//
// bf16 path (round-14, VERIFIED): same mechanism. A dbuf 2x32K @0 staged 1
// ahead, B tribuf 3x32K @64K staged 2 ahead, BOTH staged AFTER the barrier
// => WAR via the single per-iter barrier. Pre-barrier counted wait
// vmcnt(it+1<NIT ? 4 : 0) keeps only B(it+1) in flight and drains
// {A(it), B(it)} (A: 1-phase cover; B: 2-phase cover; FIFO walk verified
// for prologue/steady/tails). Per-wave counters + barrier => cross-wave
// validity (round-3 lesson).
// LDS layout per buffer: [256 rows][8 slots of 16B], phys slot = c^(row&7)
// (conflict-free ds_read_b128). Lane-linear phys-slot ownership for fp32 A
// writes (one LDS row = 128B = full bank wrap => only lane-linear is clean).
// Block swizzle: XCD-chunked remap, N-tiles of one M-slab adjacent.
// gridDim.y==4, (gx*gy)%8==0 for all launches.
// Split-K: blockIdx.z = kslice*(abmask+1)+batch.
// DUAL: bz selects operand set 1 (A2/B2/bias2/C2, no phi) vs set 0 (phi).
// KSUM (DUAL && TRANS_OUT && phi_on): epilogue column sums of the phi'd tile
// atomicAdd into ksum_out[batch*1024+col] (fused Ksum).
template<int EPI, bool A_F32, bool TRANS_OUT, bool DUAL>
__global__ __launch_bounds__(512, 2)
void gemm_bt(const void* __restrict__ Aall, const u16* __restrict__ Ball,
             const float* __restrict__ bias, const float* __restrict__ Zall,
             void* __restrict__ Call,
             int M, int N, int K, int ldA, int ldB, int ldC,
             long sAb, long sBb, long sCb, long sZb, int abmask, int kshift,
             const void* __restrict__ Aall2, const u16* __restrict__ Ball2,
             const float* __restrict__ bias2, void* __restrict__ Call2,
             float* __restrict__ ksum_out)
{
  extern __shared__ char smem[];

  const int tid  = threadIdx.x;
  const int lane = tid & 63;
  const int wave = tid >> 6;
  const int wm = wave >> 2, wn = wave & 3;   // 2x4 waves, 128x64 each
  const int fl = lane & 15;
  const int q  = lane >> 4;
  const int r4 = q * 4;

  // XCD-chunked block swizzle; consecutive remapped ids iterate the 4 N-tiles
  // of one M-tile.
  const int orig = blockIdx.x + gridDim.x * blockIdx.y;
  const int nwg8 = (gridDim.x * gridDim.y) >> 3;
  const int wsw  = (orig & 7) * nwg8 + (orig >> 3);
  const int bm0 = (wsw >> 2) * 256;          // gridDim.y == 4 in all launches
  const int bn0 = (wsw & 3) * 256;

  const int bz = blockIdx.z;
  const int abz = bz & abmask;
  const int kbase = (bz >> kshift) * K;

  const void* Asel = Aall; const u16* Bsel = Ball;
  const float* biasSel = bias; void* Csel = Call;
  bool phi_on = true;
  if constexpr (DUAL) {
    if (bz) { Asel = Aall2; Bsel = Ball2; biasSel = bias2; Csel = Call2; phi_on = false; }
  }

  const u16* Bp = Bsel + (size_t)abz * sBb + kbase;

  // ---- B staging addresses (global per-lane pre-swizzled; LDS dest linear) --
  const u16* gB[4]; int sLo[4];
  #pragma unroll
  for (int n = 0; n < 4; ++n) {
    int j = n * 512 + tid;
    int row = j >> 3, pc = j & 7, c = pc ^ (row & 7);
    gB[n] = Bp + (size_t)(bn0 + row) * ldB + c * 8;
    sLo[n] = (n * 512 + wave * 64) * 16;
  }

  // ---- fragment LDS byte offsets (ks=0; ks=1 toggles ^64) ----
  int aoff[8], boffB[4];
  #pragma unroll
  for (int i = 0; i < 8; ++i) {
    int row = wm * 128 + i * 16 + fl;
    aoff[i] = (row * 8 + (q ^ (row & 7))) * 16;
  }
  #pragma unroll
  for (int i = 0; i < 4; ++i) {
    int row = wn * 64 + i * 16 + fl;
    boffB[i] = (row * 8 + (q ^ (row & 7))) * 16;   // relative to buffer base
  }

  floatx4 zero = {0.f, 0.f, 0.f, 0.f};
  floatx4 acc[8][4];
  #pragma unroll
  for (int i = 0; i < 8; ++i)
    #pragma unroll
    for (int j = 0; j < 4; ++j) acc[i][j] = zero;

  const int NIT = K >> 6;                 // K-tiles of 64

  auto ABUF = [&](int i) -> char* { return smem + (i & 1) * 32768; };
  auto BBUF = [&](int i) -> char* { return smem + 65536 + (i % 3) * 32768; };
  auto stageB3 = [&](int k0, char* bbase) {
    #pragma unroll
    for (int n = 0; n < 4; ++n) gl_lds16(gB[n] + k0, bbase + sLo[n]);
  };

  if constexpr (A_F32) {
    const float* Af = (const float*)Asel + (size_t)abz * sAb + kbase;
    // linear phys-slot ownership: slot j = n*512 + tid
    const float* gAs[4]; int wOff[4];
    #pragma unroll
    for (int n = 0; n < 4; ++n) {
      int j = n * 512 + tid;
      int row = j >> 3, c = (j & 7) ^ (row & 7);
      gAs[n] = Af + (size_t)(bm0 + row) * ldA + c * 8;
      wOff[n] = j * 16;
    }

    float4 Ar[8];                         // single full A-tile bank (32 VGPR)
    auto aloadFull = [&](int k0) {
      #pragma unroll
      for (int n = 0; n < 4; ++n) {
        Ar[2 * n]     = *(const float4*)(gAs[n] + k0);
        Ar[2 * n + 1] = *(const float4*)(gAs[n] + k0 + 4);
      }
    };
    auto awriteFull = [&](char* base) {
      #pragma unroll
      for (int n = 0; n < 4; ++n)
        *(short8*)(base + wOff[n]) = cvt2(Ar[2 * n], Ar[2 * n + 1]);
    };

    short8 aF[4], bF[4];
    auto rdB = [&](const char* bbase, int ks) {
      #pragma unroll
      for (int i = 0; i < 4; ++i) bF[i] = *(const short8*)(bbase + (boffB[i] ^ (ks * 64)));
    };
    auto rdA = [&](const char* abase, int mh, int ks) {
      #pragma unroll
      for (int i = 0; i < 4; ++i) aF[i] = *(const short8*)(abase + (aoff[mh * 4 + i] ^ (ks * 64)));
    };
    auto mma = [&](int mh) {
      __builtin_amdgcn_s_setprio(1);
      #pragma unroll
      for (int i = 0; i < 4; ++i)
        #pragma unroll
        for (int ni = 0; ni < 4; ++ni)
          acc[mh * 4 + i][ni] =
              __builtin_amdgcn_mfma_f32_16x16x32_bf16(aF[i], bF[ni], acc[mh * 4 + i][ni], 0, 0, 0);
      __builtin_amdgcn_s_setprio(0);
    };

    // prologue (NIT >= 2 for all our shapes)
    aloadFull(0);                                       // A(0): 8
    stageB3(0, BBUF(0));                                // B(0): +4
    if (NIT > 1) stageB3(64, BBUF(1));                  // B(1): +4
    asm volatile("s_waitcnt vmcnt(8)" ::: "memory");    // A(0) landed
    awriteFull(ABUF(0));
    if (NIT > 1) aloadFull(64);                         // A(1): +8
    asm volatile("s_waitcnt vmcnt(12)" ::: "memory");   // B(0) landed
    asm volatile("s_waitcnt lgkmcnt(0)" ::: "memory");  // A(0) writes committed
    wg_barrier();                                       // tile 0 published

    for (int it = 0; it < NIT; ++it) {
      const char* Ab = ABUF(it);
      const char* Bb = BBUF(it);
      const bool pre1 = (it + 1 < NIT), pre2 = (it + 2 < NIT);
      if (pre2) stageB3((it + 2) * 64, BBUF(it + 2));
      // ---- ks = 0 ----
      rdB(Bb, 0);
      rdA(Ab, 0, 0); mma(0);
      rdA(Ab, 1, 0); mma(1);
      if (pre1) {
        if (pre2) { asm volatile("s_waitcnt vmcnt(4)" ::: "memory"); }  // A(it+1)+B(it+1) landed
        else      { asm volatile("s_waitcnt vmcnt(0)" ::: "memory"); }  // tail drain
        awriteFull(ABUF(it + 1));          // bank freed ...
        if (pre2) aloadFull((it + 2) * 64);// ... and refilled for it+2
      }
      // ---- ks = 1 ----
      rdB(Bb, 1);
      rdA(Ab, 0, 1); mma(0);
      rdA(Ab, 1, 1); mma(1);
      if (pre1) { asm volatile("s_waitcnt lgkmcnt(0)" ::: "memory"); }  // A-writes committed
      wg_barrier();                        // publish tile it+1; WAR
    }
  } else {
    // round-14 bf16 path: single-barrier deep pipeline (mechanism = R13).
    // A via gl_lds staged 1 ahead (dbuf), B staged 2 ahead (tribuf); all
    // stages AFTER the barrier; pre-barrier vmcnt keeps only B(it+1).
    const u16* Ah = (const u16*)Asel + (size_t)abz * sAb + kbase;
    const u16* gA[4];
    #pragma unroll
    for (int n = 0; n < 4; ++n) {
      int j = n * 512 + tid;
      int row = j >> 3, pc = j & 7, c = pc ^ (row & 7);
      gA[n] = Ah + (size_t)(bm0 + row) * ldA + c * 8;
    }
    auto stageA = [&](int k0, char* abase) {
      #pragma unroll
      for (int n = 0; n < 4; ++n) gl_lds16(gA[n] + k0, abase + sLo[n]);
    };
    auto compute = [&](const char* Ab, const char* Bb) {
      #pragma unroll
      for (int ks = 0; ks < 2; ++ks) {
        short8 aF[8], bF[4];
        #pragma unroll
        for (int i = 0; i < 8; ++i) aF[i] = *(const short8*)(Ab + (aoff[i] ^ (ks * 64)));
        #pragma unroll
        for (int i = 0; i < 4; ++i) bF[i] = *(const short8*)(Bb + (boffB[i] ^ (ks * 64)));
        __builtin_amdgcn_s_setprio(1);
        #pragma unroll
        for (int mi = 0; mi < 8; ++mi)
          #pragma unroll
          for (int ni = 0; ni < 4; ++ni)
            acc[mi][ni] = __builtin_amdgcn_mfma_f32_16x16x32_bf16(aF[mi], bF[ni], acc[mi][ni], 0, 0, 0);
        __builtin_amdgcn_s_setprio(0);
      }
    };
    // prologue: A(0), B(0), B(1) — first wait is the only short-cover one.
    stageA(0, ABUF(0));
    stageB3(0, BBUF(0));
    if (NIT > 1) stageB3(64, BBUF(1));
    for (int it = 0; it < NIT; ++it) {
      if (it + 1 < NIT) { asm volatile("s_waitcnt vmcnt(4)" ::: "memory"); }  // keep B(it+1); A(it),B(it) landed
      else              { asm volatile("s_waitcnt vmcnt(0)" ::: "memory"); }
      wg_barrier();                        // publish tile it (RAW); WAR gate
      if (it + 1 < NIT) stageA((it + 1) * 64, ABUF(it + 1));
      if (it + 2 < NIT) stageB3((it + 2) * 64, BBUF(it + 2));
      compute(ABUF(it), BBUF(it));
    }
  }

  if constexpr (!TRANS_OUT) {
    #pragma unroll
    for (int mi = 0; mi < 8; ++mi) {
      #pragma unroll
      for (int ni = 0; ni < 4; ++ni) {
        int col = bn0 + wn * 64 + ni * 16 + fl;
        #pragma unroll
        for (int r = 0; r < 4; ++r) {
          int row = bm0 + wm * 128 + mi * 16 + r4 + r;
          float vv = acc[mi][ni][r];
          if constexpr (EPI == EPI_PHI_BIAS) {
            vv += biasSel[col];
            if (phi_on) vv = __expf(-0.5f * vv * vv);
          }
          if constexpr (EPI == EPI_BIAS || EPI == EPI_BIAS_F32) vv += biasSel[col];
          if constexpr (EPI == EPI_ZSCALE) vv *= Zall[(size_t)abz * sZb + row];
          if constexpr (EPI == EPI_ZBIAS_F32)
            vv = vv * Zall[(size_t)abz * sZb + row] + biasSel[col];
          if constexpr (EPI == EPI_BIAS_F32 || EPI == EPI_ZBIAS_F32)
            ((float*)Csel)[(size_t)bz * sCb + (size_t)row * ldC + col] = vv;
          else
            ((u16*)Csel)[(size_t)bz * sCb + (size_t)row * ldC + col] = f2b(vv);
        }
      }
    }
  } else {
    // transpose through LDS in two 128-t-row passes, then coalesced 16B
    // stores into [4][N][4096]. sT = [256 d][136 t-pad] u16 = 69632 B.
    float ks[4] = {0.f, 0.f, 0.f, 0.f};   // fused Ksum column partials
    __syncthreads();                      // all compute reads done, smem free
    u16* sT = (u16*)smem;
    #pragma unroll
    for (int h = 0; h < 2; ++h) {
      if (wm == h) {
        #pragma unroll
        for (int mi = 0; mi < 8; ++mi) {
          #pragma unroll
          for (int ni = 0; ni < 4; ++ni) {
            int colL = wn * 64 + ni * 16 + fl;
            int row0 = mi * 16 + r4;
            float bcol = biasSel[bn0 + colL];
            ushort4 hh;
            #pragma unroll
            for (int r = 0; r < 4; ++r) {
              float vv = acc[mi][ni][r] + bcol;
              if (phi_on) vv = __expf(-0.5f * vv * vv);
              if constexpr (DUAL) ks[ni] += vv;
              ((u16*)&hh)[r] = f2b(vv);
            }
            *(ushort4*)(sT + colL * 136 + row0) = hh;
          }
        }
      }
      __syncthreads();
      #pragma unroll
      for (int i = 0; i < 8; ++i) {
        int c = i * 512 + tid;            // 4096 x 16B chunks (256 d x 128 t)
        int dloc = c >> 4, t16 = (c & 15) * 8;
        int4 vv = *(const int4*)(sT + dloc * 136 + t16);
        int gd = bn0 + dloc;
        int gt = bm0 + h * 128 + t16;
        int batch = gt >> 12, tt = gt & 4095;
        *(int4*)((u16*)Csel + ((size_t)batch * N + gd) * 4096 + tt) = vv;
      }
      __syncthreads();
    }
    if constexpr (DUAL) {
      if (phi_on) {                       // K-projection blocks: fused Ksum
        #pragma unroll
        for (int ni = 0; ni < 4; ++ni) {
          float s = ks[ni];
          s += __shfl_xor(s, 16, 64);
          s += __shfl_xor(s, 32, 64);
          if (q == 0)
            atomicAdd(ksum_out + ((bm0 >> 12) << 10) + bn0 + wn * 64 + ni * 16 + fl, s);
        }
      }
    }
  }
}

__global__ __launch_bounds__(256)
void wconv(const float* __restrict__ w0, const float* __restrict__ w1,
           const float* __restrict__ w2, const float* __restrict__ w3,
           u16* __restrict__ dst, float* __restrict__ ksum) {
  if (blockIdx.x == 0) {                 // zero Ksum [4][1024] for fused atomics
    float4 z = {0.f, 0.f, 0.f, 0.f};
    #pragma unroll
    for (int i = 0; i < 4; ++i)
      *(float4*)(ksum + threadIdx.x * 16 + i * 4) = z;
  }
  unsigned e = blockIdx.x * 256 + threadIdx.x;
  int mat = e >> 18;
  size_t off = (size_t)(e & 262143) * 4;
  const float* src = mat == 0 ? w0 : mat == 1 ? w1 : mat == 2 ? w2 : w3;
  float4 v = *(const float4*)(src + off);
  ushort4 h;
  h.x = f2b(v.x); h.y = f2b(v.y); h.z = f2b(v.z); h.w = f2b(v.w);
  *(ushort4*)(dst + (size_t)mat * 1048576 + off) = h;
}

// out[i] = round(sum over 4 K-slices of bf16 partials), 4M elems, slice stride 4M
__global__ __launch_bounds__(256)
void reduce4(const u16* __restrict__ P, u16* __restrict__ out) {
  size_t i = ((size_t)blockIdx.x * 256 + threadIdx.x) * 8;
  int4 a = *(const int4*)(P + i);
  int4 b = *(const int4*)(P + i + 4194304);
  int4 c = *(const int4*)(P + i + 8388608);
  int4 d = *(const int4*)(P + i + 12582912);
  const u16* ha = (const u16*)&a; const u16* hb = (const u16*)&b;
  const u16* hc = (const u16*)&c; const u16* hd = (const u16*)&d;
  ushort4 o0, o1;
  #pragma unroll
  for (int j = 0; j < 8; ++j) {
    float s = b2f(ha[j]) + b2f(hb[j]) + b2f(hc[j]) + b2f(hd[j]);
    ((u16*)(j < 4 ? &o0 : &o1))[j & 3] = f2b(s);
  }
  *(ushort4*)(out + i) = o0;
  *(ushort4*)(out + i + 4) = o1;
}

// Z[t] = 1/(Q[t,:]·Ksum[batch,:] + 1e-6); one wave per token
__global__ __launch_bounds__(256)
void zden(const u16* __restrict__ Qb, const float* __restrict__ Ksum,
          float* __restrict__ Z) {
  int lane = threadIdx.x & 63;
  int t = blockIdx.x * 4 + (threadIdx.x >> 6);
  const u16* qp = Qb + (size_t)t * 1024;
  const float* ks = Ksum + (size_t)(t >> 12) * 1024;
  float s = 0.f;
  #pragma unroll
  for (int i = 0; i < 2; ++i) {
    int idx = i * 512 + lane * 8;
    int4 d = *(const int4*)(qp + idx);
    const u16* h = (const u16*)&d;
    float4 k0 = *(const float4*)(ks + idx);
    float4 k1 = *(const float4*)(ks + idx + 4);
    s += b2f(h[0]) * k0.x + b2f(h[1]) * k0.y + b2f(h[2]) * k0.z + b2f(h[3]) * k0.w
       + b2f(h[4]) * k1.x + b2f(h[5]) * k1.y + b2f(h[6]) * k1.z + b2f(h[7]) * k1.w;
  }
  #pragma unroll
  for (int off = 32; off; off >>= 1) s += __shfl_xor(s, off, 64);
  if (lane == 0) Z[t] = 1.0f / (s + 1e-6f);
}

extern "C" void kernel_launch(void* const* d_in, const int* in_sizes, int n_in,
                              void* d_out, int out_size, void* d_ws, size_t ws_size,
                              hipStream_t stream) {
  const float* q  = (const float*)d_in[0];
  const float* k  = (const float*)d_in[1];
  const float* v  = (const float*)d_in[2];
  const float* Wq = (const float*)d_in[3];
  const float* bq = (const float*)d_in[4];
  const float* Wk = (const float*)d_in[5];
  const float* bk = (const float*)d_in[6];
  const float* Wv = (const float*)d_in[7];
  const float* bv = (const float*)d_in[8];
  const float* Wo = (const float*)d_in[9];
  const float* bo = (const float*)d_in[10];
  float* out = (float*)d_out;

  // workspace layout (~112.1 MiB) with aliasing:
  u16* Wqb = (u16*)d_ws;                 // 4x 1024x1024 bf16 = 8 MiB
  u16* Wkb = Wqb + 1048576;
  u16* Wvb = Wkb + 1048576;
  u16* Wob = Wvb + 1048576;
  u16* Qb  = Wob + 1048576;              // [16384][1024] bf16, 32 MiB
  u16* KT  = Qb  + 16777216;             // [4][1024][4096] bf16, 32 MiB
  u16* VT  = KT  + 16777216;             // [4][1024][4096] bf16, 32 MiB
  u16* KVr = VT  + 16777216;             // [4][1024(d)][1024(l)] bf16, 8 MiB
  float* Ksum = (float*)(KVr + 4194304); // [4][1024] f32 (atomically built)
  float* Z    = Ksum + 4096;             // [16384] f32
  u16* Pkv = Qb;   // S2 split-K partials, before Q-proj overwrites
  u16* Pg  = VT;   // G split-K partials, after VT dead
  u16* Gp  = KT;   // G' [4][1024(n)][1024(d)], after KT dead

  constexpr size_t LDS_DEEP = 163840;    // A 2x32K + B 3x32K (full 160K)

  wconv<<<4096, 256, 0, stream>>>(Wq, Wk, Wv, Wo, Wqb, Ksum);

  // K,V projections in ONE dispatch (grid z: 0=K with phi + fused Ksum,
  // 1=V bias-only). A = fp32 k / v directly (in-kernel conversion).
  dim3 gkv(64, 4, 2);
  gemm_bt<EPI_PHI_BIAS, true, true, true><<<gkv, 512, LDS_DEEP, stream>>>(
      k, Wkb, bk, nullptr, KT, 16384, 1024, 1024, 1024, 1024, 0,
      0, 0, 0, 0, 0, 30, v, Wvb, bv, VT, Ksum);

  // S2: KVr[d,l] = sum_t KT[d,t]*VT[l,t], split-K x4 (z = kslice*4+batch)
  dim3 g2(4, 4, 16);
  gemm_bt<EPI_NONE, false, false, false><<<g2, 512, LDS_DEEP, stream>>>(
      KT, VT, nullptr, nullptr, Pkv, 1024, 1024, 1024, 4096, 4096, 1024,
      4194304L, 4194304L, 1048576L, 0, 3, 2, nullptr, nullptr, nullptr, nullptr, nullptr);
  reduce4<<<2048, 256, 0, stream>>>(Pkv, KVr);

  // Q projection from fp32 q (overwrites partials region — stream-ordered)
  dim3 g1(64, 4, 1);
  gemm_bt<EPI_PHI_BIAS, true, false, false><<<g1, 512, LDS_DEEP, stream>>>(
      q, Wqb, bq, nullptr, Qb, 16384, 1024, 1024, 1024, 1024, 1024,
      0, 0, 0, 0, 0, 30, nullptr, nullptr, nullptr, nullptr, nullptr);

  zden<<<4096, 256, 0, stream>>>(Qb, Ksum, Z);

  // G'[n,d] = sum_l Wob[n,l]*KVr[d,l], split-K x4 (K=256/slice); Wo folded in.
  dim3 gg(4, 4, 16);
  gemm_bt<EPI_NONE, false, false, false><<<gg, 512, LDS_DEEP, stream>>>(
      Wob, KVr, nullptr, nullptr, Pg, 1024, 1024, 256, 1024, 1024, 1024,
      0L, 1048576L, 1048576L, 0, 3, 2, nullptr, nullptr, nullptr, nullptr, nullptr);
  reduce4<<<2048, 256, 0, stream>>>(Pg, Gp);

  // final: out[t,n] = Z[t]*(sum_d Qb[t,d]*G'[n,d]) + bo[n], fp32 out
  dim3 gf(16, 4, 4);
  gemm_bt<EPI_ZBIAS_F32, false, false, false><<<gf, 512, LDS_DEEP, stream>>>(
      Qb, Gp, bo, Z, out, 4096, 1024, 1024, 1024, 1024, 1024,
      4194304L, 1048576L, 4194304L, 4096L, 3, 30, nullptr, nullptr, nullptr, nullptr, nullptr);
}

// Round 17
// 418.244 us; speedup vs baseline: 1.1567x; 1.0039x over previous
//
#include <hip/hip_runtime.h>

typedef unsigned short u16;
typedef unsigned int u32;
typedef unsigned long long u64;

typedef __attribute__((ext_vector_type(8))) short short8;   // 8 bf16 = 4 VGPRs
typedef __attribute__((ext_vector_type(4))) float floatx4;  // MFMA accumulator

__device__ __forceinline__ float b2f(u16 h) {
  u32 u = ((u32)h) << 16;
  return __builtin_bit_cast(float, u);
}
__device__ __forceinline__ u16 f2b(float f) {
  u32 u = __builtin_bit_cast(u32, f);
  u32 r = 0x7FFFu + ((u >> 16) & 1u);  // RNE
  return (u16)((u + r) >> 16);
}

// async global->LDS, 16B per lane. LDS dest = wave-uniform base + lane*16.
__device__ __forceinline__ void gl_lds16(const void* g, void* l) {
  __builtin_amdgcn_global_load_lds(
      (__attribute__((address_space(1))) void*)(u64)g,
      (__attribute__((address_space(3))) void*)(u32)(u64)l, 16, 0, 0);
}

// raw workgroup barrier WITHOUT the compiler's vmcnt(0) drain, so
// global_load_lds prefetches stay in flight across it.
__device__ __forceinline__ void wg_barrier() {
  asm volatile("" ::: "memory");
  __builtin_amdgcn_s_barrier();
  asm volatile("" ::: "memory");
}

// trunc-pack 8 fp32 -> 8 bf16 (verified byte order, round-0 kernel)
__device__ __forceinline__ short8 cvt2(const float4& a, const float4& b) {
  union { u32 w[4]; short8 s; } cv;
  const u32* x = (const u32*)&a;
  const u32* y = (const u32*)&b;
  cv.w[0] = __builtin_amdgcn_perm(x[1], x[0], 0x07060302u);
  cv.w[1] = __builtin_amdgcn_perm(x[3], x[2], 0x07060302u);
  cv.w[2] = __builtin_amdgcn_perm(y[1], y[0], 0x07060302u);
  cv.w[3] = __builtin_amdgcn_perm(y[3], y[2], 0x07060302u);
  return cv.s;
}

enum { EPI_PHI_BIAS = 0, EPI_BIAS = 1, EPI_NONE = 2, EPI_ZSCALE = 3,
       EPI_BIAS_F32 = 4, EPI_ZBIAS_F32 = 5 };

// C[m,n] = sum_k A[m,k] * B[n,k]  (K-contiguous). 256x256x64 tile, 8 waves
// (2M x 4N, 128x64 per wave). SESSION-BEST verified structure (R13/R14/R16:
// 415.4 / 414.9 / 419.9 us): deep-in-time counted-vmcnt pipelines, one
// barrier per K-tile, every vmem wait covered by >= 1 full compute phase.
//
// A_F32: 160K LDS (A dbuf 2x32K, B tribuf 3x32K), single 32-VGPR A bank;
// A(it+2) loads issued at mid(it) right after the bank frees, B staged 2
// ahead; mid vmcnt(4) (A(it+1)+B(it+1) landed, 1-1.5 iter cover), end
// lgkmcnt(0)+barrier only. No vmem drain in the steady loop.
//
// bf16: A dbuf staged 1 ahead + B tribuf staged 2 ahead via gl_lds, both
// AFTER the barrier => WAR via the single per-iter barrier; pre-barrier
// vmcnt(it+1<NIT ? 4 : 0) keeps only B(it+1) in flight. FIFO walks verified
// for prologue/steady/tails. Per-wave counters + barrier => cross-wave
// validity (round-3 lesson).
//
// LDS layout per buffer: [256 rows][8 slots of 16B], phys slot = c^(row&7)
// (conflict-free ds_read_b128). Lane-linear phys-slot ownership for fp32 A
// writes (one LDS row = 128B = full bank wrap => only lane-linear is clean).
// Block swizzle: XCD-chunked remap, N-tiles of one M-slab adjacent.
// gridDim.y==4, (gx*gy)%8==0 for all launches.
// Split-K: blockIdx.z = kslice*(abmask+1)+batch.
// DUAL: bz selects operand set 1 (A2/B2/bias2/C2, no phi) vs set 0 (phi).
// KSUM (DUAL && TRANS_OUT && phi_on): epilogue column sums of the phi'd tile
// atomicAdd into ksum_out[batch*1024+col] (fused Ksum).
template<int EPI, bool A_F32, bool TRANS_OUT, bool DUAL>
__global__ __launch_bounds__(512, 2)
void gemm_bt(const void* __restrict__ Aall, const u16* __restrict__ Ball,
             const float* __restrict__ bias, const float* __restrict__ Zall,
             void* __restrict__ Call,
             int M, int N, int K, int ldA, int ldB, int ldC,
             long sAb, long sBb, long sCb, long sZb, int abmask, int kshift,
             const void* __restrict__ Aall2, const u16* __restrict__ Ball2,
             const float* __restrict__ bias2, void* __restrict__ Call2,
             float* __restrict__ ksum_out)
{
  extern __shared__ char smem[];

  const int tid  = threadIdx.x;
  const int lane = tid & 63;
  const int wave = tid >> 6;
  const int wm = wave >> 2, wn = wave & 3;   // 2x4 waves, 128x64 each
  const int fl = lane & 15;
  const int q  = lane >> 4;
  const int r4 = q * 4;

  // XCD-chunked block swizzle; consecutive remapped ids iterate the 4 N-tiles
  // of one M-tile.
  const int orig = blockIdx.x + gridDim.x * blockIdx.y;
  const int nwg8 = (gridDim.x * gridDim.y) >> 3;
  const int wsw  = (orig & 7) * nwg8 + (orig >> 3);
  const int bm0 = (wsw >> 2) * 256;          // gridDim.y == 4 in all launches
  const int bn0 = (wsw & 3) * 256;

  const int bz = blockIdx.z;
  const int abz = bz & abmask;
  const int kbase = (bz >> kshift) * K;

  const void* Asel = Aall; const u16* Bsel = Ball;
  const float* biasSel = bias; void* Csel = Call;
  bool phi_on = true;
  if constexpr (DUAL) {
    if (bz) { Asel = Aall2; Bsel = Ball2; biasSel = bias2; Csel = Call2; phi_on = false; }
  }

  const u16* Bp = Bsel + (size_t)abz * sBb + kbase;

  // ---- B staging addresses (global per-lane pre-swizzled; LDS dest linear) --
  const u16* gB[4]; int sLo[4];
  #pragma unroll
  for (int n = 0; n < 4; ++n) {
    int j = n * 512 + tid;
    int row = j >> 3, pc = j & 7, c = pc ^ (row & 7);
    gB[n] = Bp + (size_t)(bn0 + row) * ldB + c * 8;
    sLo[n] = (n * 512 + wave * 64) * 16;
  }

  // ---- fragment LDS byte offsets (ks=0; ks=1 toggles ^64) ----
  int aoff[8], boffB[4];
  #pragma unroll
  for (int i = 0; i < 8; ++i) {
    int row = wm * 128 + i * 16 + fl;
    aoff[i] = (row * 8 + (q ^ (row & 7))) * 16;
  }
  #pragma unroll
  for (int i = 0; i < 4; ++i) {
    int row = wn * 64 + i * 16 + fl;
    boffB[i] = (row * 8 + (q ^ (row & 7))) * 16;   // relative to buffer base
  }

  floatx4 zero = {0.f, 0.f, 0.f, 0.f};
  floatx4 acc[8][4];
  #pragma unroll
  for (int i = 0; i < 8; ++i)
    #pragma unroll
    for (int j = 0; j < 4; ++j) acc[i][j] = zero;

  const int NIT = K >> 6;                 // K-tiles of 64

  auto ABUF = [&](int i) -> char* { return smem + (i & 1) * 32768; };
  auto BBUF = [&](int i) -> char* { return smem + 65536 + (i % 3) * 32768; };
  auto stageB3 = [&](int k0, char* bbase) {
    #pragma unroll
    for (int n = 0; n < 4; ++n) gl_lds16(gB[n] + k0, bbase + sLo[n]);
  };

  if constexpr (A_F32) {
    const float* Af = (const float*)Asel + (size_t)abz * sAb + kbase;
    // linear phys-slot ownership: slot j = n*512 + tid
    const float* gAs[4]; int wOff[4];
    #pragma unroll
    for (int n = 0; n < 4; ++n) {
      int j = n * 512 + tid;
      int row = j >> 3, c = (j & 7) ^ (row & 7);
      gAs[n] = Af + (size_t)(bm0 + row) * ldA + c * 8;
      wOff[n] = j * 16;
    }

    float4 Ar[8];                         // single full A-tile bank (32 VGPR)
    auto aloadFull = [&](int k0) {
      #pragma unroll
      for (int n = 0; n < 4; ++n) {
        Ar[2 * n]     = *(const float4*)(gAs[n] + k0);
        Ar[2 * n + 1] = *(const float4*)(gAs[n] + k0 + 4);
      }
    };
    auto awriteFull = [&](char* base) {
      #pragma unroll
      for (int n = 0; n < 4; ++n)
        *(short8*)(base + wOff[n]) = cvt2(Ar[2 * n], Ar[2 * n + 1]);
    };

    short8 aF[4], bF[4];
    auto rdB = [&](const char* bbase, int ks) {
      #pragma unroll
      for (int i = 0; i < 4; ++i) bF[i] = *(const short8*)(bbase + (boffB[i] ^ (ks * 64)));
    };
    auto rdA = [&](const char* abase, int mh, int ks) {
      #pragma unroll
      for (int i = 0; i < 4; ++i) aF[i] = *(const short8*)(abase + (aoff[mh * 4 + i] ^ (ks * 64)));
    };
    auto mma = [&](int mh) {
      __builtin_amdgcn_s_setprio(1);
      #pragma unroll
      for (int i = 0; i < 4; ++i)
        #pragma unroll
        for (int ni = 0; ni < 4; ++ni)
          acc[mh * 4 + i][ni] =
              __builtin_amdgcn_mfma_f32_16x16x32_bf16(aF[i], bF[ni], acc[mh * 4 + i][ni], 0, 0, 0);
      __builtin_amdgcn_s_setprio(0);
    };

    // prologue (NIT >= 2 for all our shapes)
    aloadFull(0);                                       // A(0): 8
    stageB3(0, BBUF(0));                                // B(0): +4
    if (NIT > 1) stageB3(64, BBUF(1));                  // B(1): +4
    asm volatile("s_waitcnt vmcnt(8)" ::: "memory");    // A(0) landed
    awriteFull(ABUF(0));
    if (NIT > 1) aloadFull(64);                         // A(1): +8
    asm volatile("s_waitcnt vmcnt(12)" ::: "memory");   // B(0) landed
    asm volatile("s_waitcnt lgkmcnt(0)" ::: "memory");  // A(0) writes committed
    wg_barrier();                                       // tile 0 published

    for (int it = 0; it < NIT; ++it) {
      const char* Ab = ABUF(it);
      const char* Bb = BBUF(it);
      const bool pre1 = (it + 1 < NIT), pre2 = (it + 2 < NIT);
      if (pre2) stageB3((it + 2) * 64, BBUF(it + 2));
      // ---- ks = 0 ----
      rdB(Bb, 0);
      rdA(Ab, 0, 0); mma(0);
      rdA(Ab, 1, 0); mma(1);
      if (pre1) {
        if (pre2) { asm volatile("s_waitcnt vmcnt(4)" ::: "memory"); }  // A(it+1)+B(it+1) landed
        else      { asm volatile("s_waitcnt vmcnt(0)" ::: "memory"); }  // tail drain
        awriteFull(ABUF(it + 1));          // bank freed ...
        if (pre2) aloadFull((it + 2) * 64);// ... and refilled for it+2
      }
      // ---- ks = 1 ----
      rdB(Bb, 1);
      rdA(Ab, 0, 1); mma(0);
      rdA(Ab, 1, 1); mma(1);
      if (pre1) { asm volatile("s_waitcnt lgkmcnt(0)" ::: "memory"); }  // A-writes committed
      wg_barrier();                        // publish tile it+1; WAR
    }
  } else {
    // bf16 path: single-barrier deep pipeline (mechanism = R13).
    const u16* Ah = (const u16*)Asel + (size_t)abz * sAb + kbase;
    const u16* gA[4];
    #pragma unroll
    for (int n = 0; n < 4; ++n) {
      int j = n * 512 + tid;
      int row = j >> 3, pc = j & 7, c = pc ^ (row & 7);
      gA[n] = Ah + (size_t)(bm0 + row) * ldA + c * 8;
    }
    auto stageA = [&](int k0, char* abase) {
      #pragma unroll
      for (int n = 0; n < 4; ++n) gl_lds16(gA[n] + k0, abase + sLo[n]);
    };
    auto compute = [&](const char* Ab, const char* Bb) {
      #pragma unroll
      for (int ks = 0; ks < 2; ++ks) {
        short8 aF[8], bF[4];
        #pragma unroll
        for (int i = 0; i < 8; ++i) aF[i] = *(const short8*)(Ab + (aoff[i] ^ (ks * 64)));
        #pragma unroll
        for (int i = 0; i < 4; ++i) bF[i] = *(const short8*)(Bb + (boffB[i] ^ (ks * 64)));
        __builtin_amdgcn_s_setprio(1);
        #pragma unroll
        for (int mi = 0; mi < 8; ++mi)
          #pragma unroll
          for (int ni = 0; ni < 4; ++ni)
            acc[mi][ni] = __builtin_amdgcn_mfma_f32_16x16x32_bf16(aF[mi], bF[ni], acc[mi][ni], 0, 0, 0);
        __builtin_amdgcn_s_setprio(0);
      }
    };
    // prologue: A(0), B(0), B(1) — first wait is the only short-cover one.
    stageA(0, ABUF(0));
    stageB3(0, BBUF(0));
    if (NIT > 1) stageB3(64, BBUF(1));
    for (int it = 0; it < NIT; ++it) {
      if (it + 1 < NIT) { asm volatile("s_waitcnt vmcnt(4)" ::: "memory"); }  // keep B(it+1); A(it),B(it) landed
      else              { asm volatile("s_waitcnt vmcnt(0)" ::: "memory"); }
      wg_barrier();                        // publish tile it (RAW); WAR gate
      if (it + 1 < NIT) stageA((it + 1) * 64, ABUF(it + 1));
      if (it + 2 < NIT) stageB3((it + 2) * 64, BBUF(it + 2));
      compute(ABUF(it), BBUF(it));
    }
  }

  if constexpr (!TRANS_OUT) {
    #pragma unroll
    for (int mi = 0; mi < 8; ++mi) {
      #pragma unroll
      for (int ni = 0; ni < 4; ++ni) {
        int col = bn0 + wn * 64 + ni * 16 + fl;
        #pragma unroll
        for (int r = 0; r < 4; ++r) {
          int row = bm0 + wm * 128 + mi * 16 + r4 + r;
          float vv = acc[mi][ni][r];
          if constexpr (EPI == EPI_PHI_BIAS) {
            vv += biasSel[col];
            if (phi_on) vv = __expf(-0.5f * vv * vv);
          }
          if constexpr (EPI == EPI_BIAS || EPI == EPI_BIAS_F32) vv += biasSel[col];
          if constexpr (EPI == EPI_ZSCALE) vv *= Zall[(size_t)abz * sZb + row];
          if constexpr (EPI == EPI_ZBIAS_F32)
            vv = vv * Zall[(size_t)abz * sZb + row] + biasSel[col];
          if constexpr (EPI == EPI_BIAS_F32 || EPI == EPI_ZBIAS_F32)
            ((float*)Csel)[(size_t)bz * sCb + (size_t)row * ldC + col] = vv;
          else
            ((u16*)Csel)[(size_t)bz * sCb + (size_t)row * ldC + col] = f2b(vv);
        }
      }
    }
  } else {
    // transpose through LDS in two 128-t-row passes, then coalesced 16B
    // stores into [4][N][4096]. sT = [256 d][136 t-pad] u16 = 69632 B.
    float ks[4] = {0.f, 0.f, 0.f, 0.f};   // fused Ksum column partials
    __syncthreads();                      // all compute reads done, smem free
    u16* sT = (u16*)smem;
    #pragma unroll
    for (int h = 0; h < 2; ++h) {
      if (wm == h) {
        #pragma unroll
        for (int mi = 0; mi < 8; ++mi) {
          #pragma unroll
          for (int ni = 0; ni < 4; ++ni) {
            int colL = wn * 64 + ni * 16 + fl;
            int row0 = mi * 16 + r4;
            float bcol = biasSel[bn0 + colL];
            ushort4 hh;
            #pragma unroll
            for (int r = 0; r < 4; ++r) {
              float vv = acc[mi][ni][r] + bcol;
              if (phi_on) vv = __expf(-0.5f * vv * vv);
              if constexpr (DUAL) ks[ni] += vv;
              ((u16*)&hh)[r] = f2b(vv);
            }
            *(ushort4*)(sT + colL * 136 + row0) = hh;
          }
        }
      }
      __syncthreads();
      #pragma unroll
      for (int i = 0; i < 8; ++i) {
        int c = i * 512 + tid;            // 4096 x 16B chunks (256 d x 128 t)
        int dloc = c >> 4, t16 = (c & 15) * 8;
        int4 vv = *(const int4*)(sT + dloc * 136 + t16);
        int gd = bn0 + dloc;
        int gt = bm0 + h * 128 + t16;
        int batch = gt >> 12, tt = gt & 4095;
        *(int4*)((u16*)Csel + ((size_t)batch * N + gd) * 4096 + tt) = vv;
      }
      __syncthreads();
    }
    if constexpr (DUAL) {
      if (phi_on) {                       // K-projection blocks: fused Ksum
        #pragma unroll
        for (int ni = 0; ni < 4; ++ni) {
          float s = ks[ni];
          s += __shfl_xor(s, 16, 64);
          s += __shfl_xor(s, 32, 64);
          if (q == 0)
            atomicAdd(ksum_out + ((bm0 >> 12) << 10) + bn0 + wn * 64 + ni * 16 + fl, s);
        }
      }
    }
  }
}

__global__ __launch_bounds__(256)
void wconv(const float* __restrict__ w0, const float* __restrict__ w1,
           const float* __restrict__ w2, const float* __restrict__ w3,
           u16* __restrict__ dst, float* __restrict__ ksum) {
  if (blockIdx.x == 0) {                 // zero Ksum [4][1024] for fused atomics
    float4 z = {0.f, 0.f, 0.f, 0.f};
    #pragma unroll
    for (int i = 0; i < 4; ++i)
      *(float4*)(ksum + threadIdx.x * 16 + i * 4) = z;
  }
  unsigned e = blockIdx.x * 256 + threadIdx.x;
  int mat = e >> 18;
  size_t off = (size_t)(e & 262143) * 4;
  const float* src = mat == 0 ? w0 : mat == 1 ? w1 : mat == 2 ? w2 : w3;
  float4 v = *(const float4*)(src + off);
  ushort4 h;
  h.x = f2b(v.x); h.y = f2b(v.y); h.z = f2b(v.z); h.w = f2b(v.w);
  *(ushort4*)(dst + (size_t)mat * 1048576 + off) = h;
}

// out[i] = round(sum over 4 K-slices of bf16 partials), 4M elems, slice stride 4M
__global__ __launch_bounds__(256)
void reduce4(const u16* __restrict__ P, u16* __restrict__ out) {
  size_t i = ((size_t)blockIdx.x * 256 + threadIdx.x) * 8;
  int4 a = *(const int4*)(P + i);
  int4 b = *(const int4*)(P + i + 4194304);
  int4 c = *(const int4*)(P + i + 8388608);
  int4 d = *(const int4*)(P + i + 12582912);
  const u16* ha = (const u16*)&a; const u16* hb = (const u16*)&b;
  const u16* hc = (const u16*)&c; const u16* hd = (const u16*)&d;
  ushort4 o0, o1;
  #pragma unroll
  for (int j = 0; j < 8; ++j) {
    float s = b2f(ha[j]) + b2f(hb[j]) + b2f(hc[j]) + b2f(hd[j]);
    ((u16*)(j < 4 ? &o0 : &o1))[j & 3] = f2b(s);
  }
  *(ushort4*)(out + i) = o0;
  *(ushort4*)(out + i + 4) = o1;
}

// Z[t] = 1/(Q[t,:]·Ksum[batch,:] + 1e-6); one wave per token
__global__ __launch_bounds__(256)
void zden(const u16* __restrict__ Qb, const float* __restrict__ Ksum,
          float* __restrict__ Z) {
  int lane = threadIdx.x & 63;
  int t = blockIdx.x * 4 + (threadIdx.x >> 6);
  const u16* qp = Qb + (size_t)t * 1024;
  const float* ks = Ksum + (size_t)(t >> 12) * 1024;
  float s = 0.f;
  #pragma unroll
  for (int i = 0; i < 2; ++i) {
    int idx = i * 512 + lane * 8;
    int4 d = *(const int4*)(qp + idx);
    const u16* h = (const u16*)&d;
    float4 k0 = *(const float4*)(ks + idx);
    float4 k1 = *(const float4*)(ks + idx + 4);
    s += b2f(h[0]) * k0.x + b2f(h[1]) * k0.y + b2f(h[2]) * k0.z + b2f(h[3]) * k0.w
       + b2f(h[4]) * k1.x + b2f(h[5]) * k1.y + b2f(h[6]) * k1.z + b2f(h[7]) * k1.w;
  }
  #pragma unroll
  for (int off = 32; off; off >>= 1) s += __shfl_xor(s, off, 64);
  if (lane == 0) Z[t] = 1.0f / (s + 1e-6f);
}

extern "C" void kernel_launch(void* const* d_in, const int* in_sizes, int n_in,
                              void* d_out, int out_size, void* d_ws, size_t ws_size,
                              hipStream_t stream) {
  const float* q  = (const float*)d_in[0];
  const float* k  = (const float*)d_in[1];
  const float* v  = (const float*)d_in[2];
  const float* Wq = (const float*)d_in[3];
  const float* bq = (const float*)d_in[4];
  const float* Wk = (const float*)d_in[5];
  const float* bk = (const float*)d_in[6];
  const float* Wv = (const float*)d_in[7];
  const float* bv = (const float*)d_in[8];
  const float* Wo = (const float*)d_in[9];
  const float* bo = (const float*)d_in[10];
  float* out = (float*)d_out;

  // workspace layout (~112.1 MiB) with aliasing:
  u16* Wqb = (u16*)d_ws;                 // 4x 1024x1024 bf16 = 8 MiB
  u16* Wkb = Wqb + 1048576;
  u16* Wvb = Wkb + 1048576;
  u16* Wob = Wvb + 1048576;
  u16* Qb  = Wob + 1048576;              // [16384][1024] bf16, 32 MiB
  u16* KT  = Qb  + 16777216;             // [4][1024][4096] bf16, 32 MiB
  u16* VT  = KT  + 16777216;             // [4][1024][4096] bf16, 32 MiB
  u16* KVr = VT  + 16777216;             // [4][1024(d)][1024(l)] bf16, 8 MiB
  float* Ksum = (float*)(KVr + 4194304); // [4][1024] f32 (atomically built)
  float* Z    = Ksum + 4096;             // [16384] f32
  u16* Pkv = Qb;   // S2 split-K partials, before Q-proj overwrites
  u16* Pg  = VT;   // G split-K partials, after VT dead
  u16* Gp  = KT;   // G' [4][1024(n)][1024(d)], after KT dead

  constexpr size_t LDS_DEEP = 163840;    // A 2x32K + B 3x32K (full 160K)

  wconv<<<4096, 256, 0, stream>>>(Wq, Wk, Wv, Wo, Wqb, Ksum);

  // K,V projections in ONE dispatch (grid z: 0=K with phi + fused Ksum,
  // 1=V bias-only). A = fp32 k / v directly (in-kernel conversion).
  dim3 gkv(64, 4, 2);
  gemm_bt<EPI_PHI_BIAS, true, true, true><<<gkv, 512, LDS_DEEP, stream>>>(
      k, Wkb, bk, nullptr, KT, 16384, 1024, 1024, 1024, 1024, 0,
      0, 0, 0, 0, 0, 30, v, Wvb, bv, VT, Ksum);

  // S2: KVr[d,l] = sum_t KT[d,t]*VT[l,t], split-K x4 (z = kslice*4+batch)
  dim3 g2(4, 4, 16);
  gemm_bt<EPI_NONE, false, false, false><<<g2, 512, LDS_DEEP, stream>>>(
      KT, VT, nullptr, nullptr, Pkv, 1024, 1024, 1024, 4096, 4096, 1024,
      4194304L, 4194304L, 1048576L, 0, 3, 2, nullptr, nullptr, nullptr, nullptr, nullptr);
  reduce4<<<2048, 256, 0, stream>>>(Pkv, KVr);

  // Q projection from fp32 q (overwrites partials region — stream-ordered)
  dim3 g1(64, 4, 1);
  gemm_bt<EPI_PHI_BIAS, true, false, false><<<g1, 512, LDS_DEEP, stream>>>(
      q, Wqb, bq, nullptr, Qb, 16384, 1024, 1024, 1024, 1024, 1024,
      0, 0, 0, 0, 0, 30, nullptr, nullptr, nullptr, nullptr, nullptr);

  zden<<<4096, 256, 0, stream>>>(Qb, Ksum, Z);

  // G'[n,d] = sum_l Wob[n,l]*KVr[d,l], split-K x4 (K=256/slice); Wo folded in.
  dim3 gg(4, 4, 16);
  gemm_bt<EPI_NONE, false, false, false><<<gg, 512, LDS_DEEP, stream>>>(
      Wob, KVr, nullptr, nullptr, Pg, 1024, 1024, 256, 1024, 1024, 1024,
      0L, 1048576L, 1048576L, 0, 3, 2, nullptr, nullptr, nullptr, nullptr, nullptr);
  reduce4<<<2048, 256, 0, stream>>>(Pg, Gp);

  // final: out[t,n] = Z[t]*(sum_d Qb[t,d]*G'[n,d]) + bo[n], fp32 out
  dim3 gf(16, 4, 4);
  gemm_bt<EPI_ZBIAS_F32, false, false, false><<<gf, 512, LDS_DEEP, stream>>>(
      Qb, Gp, bo, Z, out, 4096, 1024, 1024, 1024, 1024, 1024,
      4194304L, 1048576L, 4194304L, 4096L, 3, 30, nullptr, nullptr, nullptr, nullptr, nullptr);
}

// Round 18
// 418.153 us; speedup vs baseline: 1.1570x; 1.0002x over previous
//
#include <hip/hip_runtime.h>

typedef unsigned short u16;
typedef unsigned int u32;
typedef unsigned long long u64;

typedef __attribute__((ext_vector_type(8))) short short8;   // 8 bf16 = 4 VGPRs
typedef __attribute__((ext_vector_type(4))) float floatx4;  // MFMA accumulator

__device__ __forceinline__ float b2f(u16 h) {
  u32 u = ((u32)h) << 16;
  return __builtin_bit_cast(float, u);
}
__device__ __forceinline__ u16 f2b(float f) {
  u32 u = __builtin_bit_cast(u32, f);
  u32 r = 0x7FFFu + ((u >> 16) & 1u);  // RNE
  return (u16)((u + r) >> 16);
}

// async global->LDS, 16B per lane. LDS dest = wave-uniform base + lane*16.
__device__ __forceinline__ void gl_lds16(const void* g, void* l) {
  __builtin_amdgcn_global_load_lds(
      (__attribute__((address_space(1))) void*)(u64)g,
      (__attribute__((address_space(3))) void*)(u32)(u64)l, 16, 0, 0);
}

// raw workgroup barrier WITHOUT the compiler's vmcnt(0) drain, so
// global_load_lds prefetches stay in flight across it.
__device__ __forceinline__ void wg_barrier() {
  asm volatile("" ::: "memory");
  __builtin_amdgcn_s_barrier();
  asm volatile("" ::: "memory");
}

// trunc-pack 8 fp32 -> 8 bf16 (verified byte order, round-0 kernel)
__device__ __forceinline__ short8 cvt2(const float4& a, const float4& b) {
  union { u32 w[4]; short8 s; } cv;
  const u32* x = (const u32*)&a;
  const u32* y = (const u32*)&b;
  cv.w[0] = __builtin_amdgcn_perm(x[1], x[0], 0x07060302u);
  cv.w[1] = __builtin_amdgcn_perm(x[3], x[2], 0x07060302u);
  cv.w[2] = __builtin_amdgcn_perm(y[1], y[0], 0x07060302u);
  cv.w[3] = __builtin_amdgcn_perm(y[3], y[2], 0x07060302u);
  return cv.s;
}

enum { EPI_PHI_BIAS = 0, EPI_BIAS = 1, EPI_NONE = 2, EPI_ZSCALE = 3,
       EPI_BIAS_F32 = 4, EPI_ZBIAS_F32 = 5 };

// C[m,n] = sum_k A[m,k] * B[n,k]  (K-contiguous). 256x256x64 tile, 8 waves
// (2M x 4N, 128x64 per wave). SESSION-BEST verified structure (R13/R14/R16/
// R17: 415.4 / 414.9 / 419.9 / 418.2 us): deep-in-time counted-vmcnt
// pipelines, one barrier per K-tile, every vmem wait covered by >= 1 full
// compute phase.
//
// A_F32: 160K LDS (A dbuf 2x32K, B tribuf 3x32K), single 32-VGPR A bank;
// A(it+2) loads issued at mid(it) right after the bank frees, B staged 2
// ahead; mid vmcnt(4) (A(it+1)+B(it+1) landed, 1-1.5 iter cover), end
// lgkmcnt(0)+barrier only. No vmem drain in the steady loop.
//
// bf16: A dbuf staged 1 ahead + B tribuf staged 2 ahead via gl_lds, both
// AFTER the barrier => WAR via the single per-iter barrier; pre-barrier
// vmcnt(it+1<NIT ? 4 : 0) keeps only B(it+1) in flight. FIFO walks verified
// for prologue/steady/tails. Per-wave counters + barrier => cross-wave
// validity (round-3 lesson).
//
// LDS layout per buffer: [256 rows][8 slots of 16B], phys slot = c^(row&7)
// (conflict-free ds_read_b128). Lane-linear phys-slot ownership for fp32 A
// writes (one LDS row = 128B = full bank wrap => only lane-linear is clean).
// Block swizzle: XCD-chunked remap, N-tiles of one M-slab adjacent.
// gridDim.y==4, (gx*gy)%8==0 for all launches.
// Split-K: blockIdx.z = kslice*(abmask+1)+batch.
// DUAL: bz selects operand set 1 (A2/B2/bias2/C2, no phi) vs set 0 (phi).
// KSUM (DUAL && TRANS_OUT && phi_on): epilogue column sums of the phi'd tile
// atomicAdd into ksum_out[batch*1024+col] (fused Ksum).
template<int EPI, bool A_F32, bool TRANS_OUT, bool DUAL>
__global__ __launch_bounds__(512, 2)
void gemm_bt(const void* __restrict__ Aall, const u16* __restrict__ Ball,
             const float* __restrict__ bias, const float* __restrict__ Zall,
             void* __restrict__ Call,
             int M, int N, int K, int ldA, int ldB, int ldC,
             long sAb, long sBb, long sCb, long sZb, int abmask, int kshift,
             const void* __restrict__ Aall2, const u16* __restrict__ Ball2,
             const float* __restrict__ bias2, void* __restrict__ Call2,
             float* __restrict__ ksum_out)
{
  extern __shared__ char smem[];

  const int tid  = threadIdx.x;
  const int lane = tid & 63;
  const int wave = tid >> 6;
  const int wm = wave >> 2, wn = wave & 3;   // 2x4 waves, 128x64 each
  const int fl = lane & 15;
  const int q  = lane >> 4;
  const int r4 = q * 4;

  // XCD-chunked block swizzle; consecutive remapped ids iterate the 4 N-tiles
  // of one M-tile.
  const int orig = blockIdx.x + gridDim.x * blockIdx.y;
  const int nwg8 = (gridDim.x * gridDim.y) >> 3;
  const int wsw  = (orig & 7) * nwg8 + (orig >> 3);
  const int bm0 = (wsw >> 2) * 256;          // gridDim.y == 4 in all launches
  const int bn0 = (wsw & 3) * 256;

  const int bz = blockIdx.z;
  const int abz = bz & abmask;
  const int kbase = (bz >> kshift) * K;

  const void* Asel = Aall; const u16* Bsel = Ball;
  const float* biasSel = bias; void* Csel = Call;
  bool phi_on = true;
  if constexpr (DUAL) {
    if (bz) { Asel = Aall2; Bsel = Ball2; biasSel = bias2; Csel = Call2; phi_on = false; }
  }

  const u16* Bp = Bsel + (size_t)abz * sBb + kbase;

  // ---- B staging addresses (global per-lane pre-swizzled; LDS dest linear) --
  const u16* gB[4]; int sLo[4];
  #pragma unroll
  for (int n = 0; n < 4; ++n) {
    int j = n * 512 + tid;
    int row = j >> 3, pc = j & 7, c = pc ^ (row & 7);
    gB[n] = Bp + (size_t)(bn0 + row) * ldB + c * 8;
    sLo[n] = (n * 512 + wave * 64) * 16;
  }

  // ---- fragment LDS byte offsets (ks=0; ks=1 toggles ^64) ----
  int aoff[8], boffB[4];
  #pragma unroll
  for (int i = 0; i < 8; ++i) {
    int row = wm * 128 + i * 16 + fl;
    aoff[i] = (row * 8 + (q ^ (row & 7))) * 16;
  }
  #pragma unroll
  for (int i = 0; i < 4; ++i) {
    int row = wn * 64 + i * 16 + fl;
    boffB[i] = (row * 8 + (q ^ (row & 7))) * 16;   // relative to buffer base
  }

  floatx4 zero = {0.f, 0.f, 0.f, 0.f};
  floatx4 acc[8][4];
  #pragma unroll
  for (int i = 0; i < 8; ++i)
    #pragma unroll
    for (int j = 0; j < 4; ++j) acc[i][j] = zero;

  const int NIT = K >> 6;                 // K-tiles of 64

  auto ABUF = [&](int i) -> char* { return smem + (i & 1) * 32768; };
  auto BBUF = [&](int i) -> char* { return smem + 65536 + (i % 3) * 32768; };
  auto stageB3 = [&](int k0, char* bbase) {
    #pragma unroll
    for (int n = 0; n < 4; ++n) gl_lds16(gB[n] + k0, bbase + sLo[n]);
  };

  if constexpr (A_F32) {
    const float* Af = (const float*)Asel + (size_t)abz * sAb + kbase;
    // linear phys-slot ownership: slot j = n*512 + tid
    const float* gAs[4]; int wOff[4];
    #pragma unroll
    for (int n = 0; n < 4; ++n) {
      int j = n * 512 + tid;
      int row = j >> 3, c = (j & 7) ^ (row & 7);
      gAs[n] = Af + (size_t)(bm0 + row) * ldA + c * 8;
      wOff[n] = j * 16;
    }

    float4 Ar[8];                         // single full A-tile bank (32 VGPR)
    auto aloadFull = [&](int k0) {
      #pragma unroll
      for (int n = 0; n < 4; ++n) {
        Ar[2 * n]     = *(const float4*)(gAs[n] + k0);
        Ar[2 * n + 1] = *(const float4*)(gAs[n] + k0 + 4);
      }
    };
    auto awriteFull = [&](char* base) {
      #pragma unroll
      for (int n = 0; n < 4; ++n)
        *(short8*)(base + wOff[n]) = cvt2(Ar[2 * n], Ar[2 * n + 1]);
    };

    short8 aF[4], bF[4];
    auto rdB = [&](const char* bbase, int ks) {
      #pragma unroll
      for (int i = 0; i < 4; ++i) bF[i] = *(const short8*)(bbase + (boffB[i] ^ (ks * 64)));
    };
    auto rdA = [&](const char* abase, int mh, int ks) {
      #pragma unroll
      for (int i = 0; i < 4; ++i) aF[i] = *(const short8*)(abase + (aoff[mh * 4 + i] ^ (ks * 64)));
    };
    auto mma = [&](int mh) {
      __builtin_amdgcn_s_setprio(1);
      #pragma unroll
      for (int i = 0; i < 4; ++i)
        #pragma unroll
        for (int ni = 0; ni < 4; ++ni)
          acc[mh * 4 + i][ni] =
              __builtin_amdgcn_mfma_f32_16x16x32_bf16(aF[i], bF[ni], acc[mh * 4 + i][ni], 0, 0, 0);
      __builtin_amdgcn_s_setprio(0);
    };

    // prologue (NIT >= 2 for all our shapes)
    aloadFull(0);                                       // A(0): 8
    stageB3(0, BBUF(0));                                // B(0): +4
    if (NIT > 1) stageB3(64, BBUF(1));                  // B(1): +4
    asm volatile("s_waitcnt vmcnt(8)" ::: "memory");    // A(0) landed
    awriteFull(ABUF(0));
    if (NIT > 1) aloadFull(64);                         // A(1): +8
    asm volatile("s_waitcnt vmcnt(12)" ::: "memory");   // B(0) landed
    asm volatile("s_waitcnt lgkmcnt(0)" ::: "memory");  // A(0) writes committed
    wg_barrier();                                       // tile 0 published

    for (int it = 0; it < NIT; ++it) {
      const char* Ab = ABUF(it);
      const char* Bb = BBUF(it);
      const bool pre1 = (it + 1 < NIT), pre2 = (it + 2 < NIT);
      if (pre2) stageB3((it + 2) * 64, BBUF(it + 2));
      // ---- ks = 0 ----
      rdB(Bb, 0);
      rdA(Ab, 0, 0); mma(0);
      rdA(Ab, 1, 0); mma(1);
      if (pre1) {
        if (pre2) { asm volatile("s_waitcnt vmcnt(4)" ::: "memory"); }  // A(it+1)+B(it+1) landed
        else      { asm volatile("s_waitcnt vmcnt(0)" ::: "memory"); }  // tail drain
        awriteFull(ABUF(it + 1));          // bank freed ...
        if (pre2) aloadFull((it + 2) * 64);// ... and refilled for it+2
      }
      // ---- ks = 1 ----
      rdB(Bb, 1);
      rdA(Ab, 0, 1); mma(0);
      rdA(Ab, 1, 1); mma(1);
      if (pre1) { asm volatile("s_waitcnt lgkmcnt(0)" ::: "memory"); }  // A-writes committed
      wg_barrier();                        // publish tile it+1; WAR
    }
  } else {
    // bf16 path: single-barrier deep pipeline (mechanism = R13).
    const u16* Ah = (const u16*)Asel + (size_t)abz * sAb + kbase;
    const u16* gA[4];
    #pragma unroll
    for (int n = 0; n < 4; ++n) {
      int j = n * 512 + tid;
      int row = j >> 3, pc = j & 7, c = pc ^ (row & 7);
      gA[n] = Ah + (size_t)(bm0 + row) * ldA + c * 8;
    }
    auto stageA = [&](int k0, char* abase) {
      #pragma unroll
      for (int n = 0; n < 4; ++n) gl_lds16(gA[n] + k0, abase + sLo[n]);
    };
    auto compute = [&](const char* Ab, const char* Bb) {
      #pragma unroll
      for (int ks = 0; ks < 2; ++ks) {
        short8 aF[8], bF[4];
        #pragma unroll
        for (int i = 0; i < 8; ++i) aF[i] = *(const short8*)(Ab + (aoff[i] ^ (ks * 64)));
        #pragma unroll
        for (int i = 0; i < 4; ++i) bF[i] = *(const short8*)(Bb + (boffB[i] ^ (ks * 64)));
        __builtin_amdgcn_s_setprio(1);
        #pragma unroll
        for (int mi = 0; mi < 8; ++mi)
          #pragma unroll
          for (int ni = 0; ni < 4; ++ni)
            acc[mi][ni] = __builtin_amdgcn_mfma_f32_16x16x32_bf16(aF[mi], bF[ni], acc[mi][ni], 0, 0, 0);
        __builtin_amdgcn_s_setprio(0);
      }
    };
    // prologue: A(0), B(0), B(1) — first wait is the only short-cover one.
    stageA(0, ABUF(0));
    stageB3(0, BBUF(0));
    if (NIT > 1) stageB3(64, BBUF(1));
    for (int it = 0; it < NIT; ++it) {
      if (it + 1 < NIT) { asm volatile("s_waitcnt vmcnt(4)" ::: "memory"); }  // keep B(it+1); A(it),B(it) landed
      else              { asm volatile("s_waitcnt vmcnt(0)" ::: "memory"); }
      wg_barrier();                        // publish tile it (RAW); WAR gate
      if (it + 1 < NIT) stageA((it + 1) * 64, ABUF(it + 1));
      if (it + 2 < NIT) stageB3((it + 2) * 64, BBUF(it + 2));
      compute(ABUF(it), BBUF(it));
    }
  }

  if constexpr (!TRANS_OUT) {
    #pragma unroll
    for (int mi = 0; mi < 8; ++mi) {
      #pragma unroll
      for (int ni = 0; ni < 4; ++ni) {
        int col = bn0 + wn * 64 + ni * 16 + fl;
        #pragma unroll
        for (int r = 0; r < 4; ++r) {
          int row = bm0 + wm * 128 + mi * 16 + r4 + r;
          float vv = acc[mi][ni][r];
          if constexpr (EPI == EPI_PHI_BIAS) {
            vv += biasSel[col];
            if (phi_on) vv = __expf(-0.5f * vv * vv);
          }
          if constexpr (EPI == EPI_BIAS || EPI == EPI_BIAS_F32) vv += biasSel[col];
          if constexpr (EPI == EPI_ZSCALE) vv *= Zall[(size_t)abz * sZb + row];
          if constexpr (EPI == EPI_ZBIAS_F32)
            vv = vv * Zall[(size_t)abz * sZb + row] + biasSel[col];
          if constexpr (EPI == EPI_BIAS_F32 || EPI == EPI_ZBIAS_F32)
            ((float*)Csel)[(size_t)bz * sCb + (size_t)row * ldC + col] = vv;
          else
            ((u16*)Csel)[(size_t)bz * sCb + (size_t)row * ldC + col] = f2b(vv);
        }
      }
    }
  } else {
    // transpose through LDS in two 128-t-row passes, then coalesced 16B
    // stores into [4][N][4096]. sT = [256 d][136 t-pad] u16 = 69632 B.
    float ks[4] = {0.f, 0.f, 0.f, 0.f};   // fused Ksum column partials
    __syncthreads();                      // all compute reads done, smem free
    u16* sT = (u16*)smem;
    #pragma unroll
    for (int h = 0; h < 2; ++h) {
      if (wm == h) {
        #pragma unroll
        for (int mi = 0; mi < 8; ++mi) {
          #pragma unroll
          for (int ni = 0; ni < 4; ++ni) {
            int colL = wn * 64 + ni * 16 + fl;
            int row0 = mi * 16 + r4;
            float bcol = biasSel[bn0 + colL];
            ushort4 hh;
            #pragma unroll
            for (int r = 0; r < 4; ++r) {
              float vv = acc[mi][ni][r] + bcol;
              if (phi_on) vv = __expf(-0.5f * vv * vv);
              if constexpr (DUAL) ks[ni] += vv;
              ((u16*)&hh)[r] = f2b(vv);
            }
            *(ushort4*)(sT + colL * 136 + row0) = hh;
          }
        }
      }
      __syncthreads();
      #pragma unroll
      for (int i = 0; i < 8; ++i) {
        int c = i * 512 + tid;            // 4096 x 16B chunks (256 d x 128 t)
        int dloc = c >> 4, t16 = (c & 15) * 8;
        int4 vv = *(const int4*)(sT + dloc * 136 + t16);
        int gd = bn0 + dloc;
        int gt = bm0 + h * 128 + t16;
        int batch = gt >> 12, tt = gt & 4095;
        *(int4*)((u16*)Csel + ((size_t)batch * N + gd) * 4096 + tt) = vv;
      }
      __syncthreads();
    }
    if constexpr (DUAL) {
      if (phi_on) {                       // K-projection blocks: fused Ksum
        #pragma unroll
        for (int ni = 0; ni < 4; ++ni) {
          float s = ks[ni];
          s += __shfl_xor(s, 16, 64);
          s += __shfl_xor(s, 32, 64);
          if (q == 0)
            atomicAdd(ksum_out + ((bm0 >> 12) << 10) + bn0 + wn * 64 + ni * 16 + fl, s);
        }
      }
    }
  }
}

__global__ __launch_bounds__(256)
void wconv(const float* __restrict__ w0, const float* __restrict__ w1,
           const float* __restrict__ w2, const float* __restrict__ w3,
           u16* __restrict__ dst, float* __restrict__ ksum) {
  if (blockIdx.x == 0) {                 // zero Ksum [4][1024] for fused atomics
    float4 z = {0.f, 0.f, 0.f, 0.f};
    #pragma unroll
    for (int i = 0; i < 4; ++i)
      *(float4*)(ksum + threadIdx.x * 16 + i * 4) = z;
  }
  unsigned e = blockIdx.x * 256 + threadIdx.x;
  int mat = e >> 18;
  size_t off = (size_t)(e & 262143) * 4;
  const float* src = mat == 0 ? w0 : mat == 1 ? w1 : mat == 2 ? w2 : w3;
  float4 v = *(const float4*)(src + off);
  ushort4 h;
  h.x = f2b(v.x); h.y = f2b(v.y); h.z = f2b(v.z); h.w = f2b(v.w);
  *(ushort4*)(dst + (size_t)mat * 1048576 + off) = h;
}

// out[i] = round(sum over 4 K-slices of bf16 partials), 4M elems, slice stride 4M
__global__ __launch_bounds__(256)
void reduce4(const u16* __restrict__ P, u16* __restrict__ out) {
  size_t i = ((size_t)blockIdx.x * 256 + threadIdx.x) * 8;
  int4 a = *(const int4*)(P + i);
  int4 b = *(const int4*)(P + i + 4194304);
  int4 c = *(const int4*)(P + i + 8388608);
  int4 d = *(const int4*)(P + i + 12582912);
  const u16* ha = (const u16*)&a; const u16* hb = (const u16*)&b;
  const u16* hc = (const u16*)&c; const u16* hd = (const u16*)&d;
  ushort4 o0, o1;
  #pragma unroll
  for (int j = 0; j < 8; ++j) {
    float s = b2f(ha[j]) + b2f(hb[j]) + b2f(hc[j]) + b2f(hd[j]);
    ((u16*)(j < 4 ? &o0 : &o1))[j & 3] = f2b(s);
  }
  *(ushort4*)(out + i) = o0;
  *(ushort4*)(out + i + 4) = o1;
}

// Z[t] = 1/(Q[t,:]·Ksum[batch,:] + 1e-6); one wave per token
__global__ __launch_bounds__(256)
void zden(const u16* __restrict__ Qb, const float* __restrict__ Ksum,
          float* __restrict__ Z) {
  int lane = threadIdx.x & 63;
  int t = blockIdx.x * 4 + (threadIdx.x >> 6);
  const u16* qp = Qb + (size_t)t * 1024;
  const float* ks = Ksum + (size_t)(t >> 12) * 1024;
  float s = 0.f;
  #pragma unroll
  for (int i = 0; i < 2; ++i) {
    int idx = i * 512 + lane * 8;
    int4 d = *(const int4*)(qp + idx);
    const u16* h = (const u16*)&d;
    float4 k0 = *(const float4*)(ks + idx);
    float4 k1 = *(const float4*)(ks + idx + 4);
    s += b2f(h[0]) * k0.x + b2f(h[1]) * k0.y + b2f(h[2]) * k0.z + b2f(h[3]) * k0.w
       + b2f(h[4]) * k1.x + b2f(h[5]) * k1.y + b2f(h[6]) * k1.z + b2f(h[7]) * k1.w;
  }
  #pragma unroll
  for (int off = 32; off; off >>= 1) s += __shfl_xor(s, off, 64);
  if (lane == 0) Z[t] = 1.0f / (s + 1e-6f);
}

extern "C" void kernel_launch(void* const* d_in, const int* in_sizes, int n_in,
                              void* d_out, int out_size, void* d_ws, size_t ws_size,
                              hipStream_t stream) {
  const float* q  = (const float*)d_in[0];
  const float* k  = (const float*)d_in[1];
  const float* v  = (const float*)d_in[2];
  const float* Wq = (const float*)d_in[3];
  const float* bq = (const float*)d_in[4];
  const float* Wk = (const float*)d_in[5];
  const float* bk = (const float*)d_in[6];
  const float* Wv = (const float*)d_in[7];
  const float* bv = (const float*)d_in[8];
  const float* Wo = (const float*)d_in[9];
  const float* bo = (const float*)d_in[10];
  float* out = (float*)d_out;

  // workspace layout (~112.1 MiB) with aliasing:
  u16* Wqb = (u16*)d_ws;                 // 4x 1024x1024 bf16 = 8 MiB
  u16* Wkb = Wqb + 1048576;
  u16* Wvb = Wkb + 1048576;
  u16* Wob = Wvb + 1048576;
  u16* Qb  = Wob + 1048576;              // [16384][1024] bf16, 32 MiB
  u16* KT  = Qb  + 16777216;             // [4][1024][4096] bf16, 32 MiB
  u16* VT  = KT  + 16777216;             // [4][1024][4096] bf16, 32 MiB
  u16* KVr = VT  + 16777216;             // [4][1024(d)][1024(l)] bf16, 8 MiB
  float* Ksum = (float*)(KVr + 4194304); // [4][1024] f32 (atomically built)
  float* Z    = Ksum + 4096;             // [16384] f32
  u16* Pkv = Qb;   // S2 split-K partials, before Q-proj overwrites
  u16* Pg  = VT;   // G split-K partials, after VT dead
  u16* Gp  = KT;   // G' [4][1024(n)][1024(d)], after KT dead

  constexpr size_t LDS_DEEP = 163840;    // A 2x32K + B 3x32K (full 160K)

  wconv<<<4096, 256, 0, stream>>>(Wq, Wk, Wv, Wo, Wqb, Ksum);

  // K,V projections in ONE dispatch (grid z: 0=K with phi + fused Ksum,
  // 1=V bias-only). A = fp32 k / v directly (in-kernel conversion).
  dim3 gkv(64, 4, 2);
  gemm_bt<EPI_PHI_BIAS, true, true, true><<<gkv, 512, LDS_DEEP, stream>>>(
      k, Wkb, bk, nullptr, KT, 16384, 1024, 1024, 1024, 1024, 0,
      0, 0, 0, 0, 0, 30, v, Wvb, bv, VT, Ksum);

  // S2: KVr[d,l] = sum_t KT[d,t]*VT[l,t], split-K x4 (z = kslice*4+batch)
  dim3 g2(4, 4, 16);
  gemm_bt<EPI_NONE, false, false, false><<<g2, 512, LDS_DEEP, stream>>>(
      KT, VT, nullptr, nullptr, Pkv, 1024, 1024, 1024, 4096, 4096, 1024,
      4194304L, 4194304L, 1048576L, 0, 3, 2, nullptr, nullptr, nullptr, nullptr, nullptr);
  reduce4<<<2048, 256, 0, stream>>>(Pkv, KVr);

  // Q projection from fp32 q (overwrites partials region — stream-ordered)
  dim3 g1(64, 4, 1);
  gemm_bt<EPI_PHI_BIAS, true, false, false><<<g1, 512, LDS_DEEP, stream>>>(
      q, Wqb, bq, nullptr, Qb, 16384, 1024, 1024, 1024, 1024, 1024,
      0, 0, 0, 0, 0, 30, nullptr, nullptr, nullptr, nullptr, nullptr);

  zden<<<4096, 256, 0, stream>>>(Qb, Ksum, Z);

  // G'[n,d] = sum_l Wob[n,l]*KVr[d,l], split-K x4 (K=256/slice); Wo folded in.
  dim3 gg(4, 4, 16);
  gemm_bt<EPI_NONE, false, false, false><<<gg, 512, LDS_DEEP, stream>>>(
      Wob, KVr, nullptr, nullptr, Pg, 1024, 1024, 256, 1024, 1024, 1024,
      0L, 1048576L, 1048576L, 0, 3, 2, nullptr, nullptr, nullptr, nullptr, nullptr);
  reduce4<<<2048, 256, 0, stream>>>(Pg, Gp);

  // final: out[t,n] = Z[t]*(sum_d Qb[t,d]*G'[n,d]) + bo[n], fp32 out
  dim3 gf(16, 4, 4);
  gemm_bt<EPI_ZBIAS_F32, false, false, false><<<gf, 512, LDS_DEEP, stream>>>(
      Qb, Gp, bo, Z, out, 4096, 1024, 1024, 1024, 1024, 1024,
      4194304L, 1048576L, 4194304L, 4096L, 3, 30, nullptr, nullptr, nullptr, nullptr, nullptr);
}